// Round 15
// baseline (945.637 us; speedup 1.0000x reference)
//
#include <hip/hip_runtime.h>
#include <math.h>

#define N    111
#define NR   112      // padded row/col stride for Ag and Xs
#define NE   4000
#define KP   100
#define APs  104      // Ap col stride
#define CA   56
#define NT   1024     // 16 waves = 4/SIMD; occupancy cap for 160KB-LDS blocks (R14)

// permuted row -> original node id. rows 0..54 LEFT, 55 = node82, 56..110 RIGHT, 111 pad
__device__ __constant__ int d_P2O[112] = {
  6,5,55,1,98,71,73,77,63,96,79,15,104,4,25,23,41,43,45,17,61,65,59,57,86,21,
  35,37,39,94,110,3,69,81,84,100,102,106,47,27,75,2,67,19,49,31,33,108,51,53,
  88,90,92,29,0,
  82,
  13,12,54,8,97,70,72,76,62,95,78,14,103,11,24,22,40,42,44,16,60,64,58,56,85,
  20,34,36,38,93,109,10,68,80,83,99,101,105,46,26,74,9,66,18,48,30,32,107,50,
  52,87,89,91,28,7,
  111};

// flat LDS float pool offsets (floats)
#define OFF_A 0        // Ag 112x112=12544 -> Ap 100x104 -> assS 111x56 (6216) + HcS 56x20 (@+6216)
#define OFF_B 12544    // Xs 111x112 (P3) -> {W2s 2x1280 | Wg1s 400 @+2560} -> {TC|Tx1|Tx2|TC2} -> s2S 111x56
#define OFF_C 24976    // T64 112x64=7168 -> T20x 112x20=2240 -> Wcs 3x1120 (P16)
#define OFF_D 32144    // H1 112x64=7168 (P3: Wlds stage, row111=0) -> {H2 | H2g @ +2240}
#define FSZ   39312

__device__ __forceinline__ float lrelu(float h) { return h > 0.f ? h : 0.01f * h; }

// R11: capped unrolls (no spills). R12: 7-row blocking. R13 transpose REVERTED
// (bank conflicts). R14: NT=1024, occupancy 48% (cap). R15: dual accumulators in
// all long-chain inner loops (halve dependent-FMA latency), Wg1 staged in LDS
// (kills 45K global loads/block in P7), P15a folded into P14 (one less barrier).
__global__ __launch_bounds__(NT, 1)
void brain_fused(const float* __restrict__ features,
                 const float* __restrict__ edge_attr,
                 const int*   __restrict__ edge_index,
                 const float* __restrict__ Wl1, const float* __restrict__ bl1,
                 const float* __restrict__ Wr1, const float* __restrict__ br1,
                 const float* __restrict__ Wl2, const float* __restrict__ bl2,
                 const float* __restrict__ Wr2, const float* __restrict__ br2,
                 const float* __restrict__ Wg1, const float* __restrict__ bg1,
                 const float* __restrict__ Wrel, const float* __restrict__ brel,
                 const float* __restrict__ Wroot,
                 const float* __restrict__ Wc0, const float* __restrict__ Wc1,
                 const float* __restrict__ Wc2, const float* __restrict__ bc,
                 float* __restrict__ out)
{
    __shared__ __align__(16) float F[FSZ];
    __shared__ float disH[112], disG[112], disC[112], scoreS[112];
    __shared__ int o2rS[112], mapRank[112], permSh[KP], spSh[KP];

    float* Ag   = F + OFF_A;            // 112x112
    float* Ap   = F + OFF_A;            // 100x104
    float* assS = F + OFF_A;            // 111x56
    float* HcS  = F + OFF_A + 6216;     // 56x20
    float* Xs   = F + OFF_B;            // 111x112 permuted rows, col111=0 (P3)
    float* W2s  = F + OFF_B;            // Wl2|Wr2 (2x1280) during P5
    float* Wg1s = F + OFF_B + 2560;     // 400 floats (P7)
    float* TC   = F + OFF_B;            // 104x20
    float* Tx1  = F + OFF_B + 2080;     // 100x20
    float* Tx2  = F + OFF_B + 4080;     // 100x20
    float* TC2  = F + OFF_B + 6160;     // 104x20 (disC*Tx1, written by P14)
    float* s2S  = F + OFF_B;            // 111x56 (after P16b; TC2 dead by then)
    float* T64  = F + OFF_C;            // 112x64
    float* T20x = F + OFF_C;            // 112x20
    float* Wcs  = F + OFF_C;            // Wc0|Wc1|Wc2 3x1120 (P16)
    float* H1   = F + OFF_D;            // 112x64
    float* Wlds = F + OFF_D;            // 112x64 W1 stage during P3 (row111=0)
    float* H2   = F + OFF_D;            // 112x20
    float* H2g  = F + OFF_D + 2240;     // 112x20

    const int b    = blockIdx.x;
    const int tid  = threadIdx.x;
    const int lane = tid & 63;
    const int wv   = tid >> 6;          // 0..15
    const float* x = features + (size_t)b * (N * N);

    // ---- P0: zero Ag, T64; build orig->row map ----
    for (int o = tid; o < 12544; o += NT) Ag[o] = 0.f;
    for (int o = tid; o < 7168;  o += NT) T64[o] = 0.f;
    if (tid < 112) o2rS[d_P2O[tid]] = tid;
    __syncthreads();

    // ---- P1a: scatter edges into Ag[t,s] (permuted) ----
    #pragma unroll 2
    for (int e = tid; e < NE; e += NT) {
        int s = o2rS[edge_index[e]];
        int t = o2rS[edge_index[NE + e]];
        atomicAdd(&Ag[t * NR + s], edge_attr[(size_t)b * NE + e]);
    }
    __syncthreads();

    // ---- P1b: stage x, permuted rows, stride 112, col111=0 ----
    #pragma unroll 2
    for (int o = tid; o < N * NR; o += NT) {
        int r = o / NR, cc = o % NR;
        Xs[o] = (cc < N) ? x[d_P2O[r] * N + cc] : 0.f;
    }
    __syncthreads();

    // ---- P2: degrees (wave/row over 16 waves, butterfly) ----
    #pragma unroll 1
    for (int k = 0; k < 7; ++k) {
        int r = wv + 16 * k;
        if (r >= 112) continue;
        if (r == 111) { if (lane == 0) { disH[111] = 0.f; disG[111] = 0.f; } continue; }
        float a0 = Ag[r * NR + lane];
        float a1 = (lane < 48) ? Ag[r * NR + 64 + lane] : 0.f;
        float sG = a0 + a1;
        float sH;
        if (r < 55)       sH = (lane < 55) ? a0 : 0.f;
        else if (r >= 56) sH = ((lane >= 56) ? a0 : 0.f) + ((lane < 47) ? a1 : 0.f);
        else              sH = 0.f;
        #pragma unroll
        for (int m = 1; m < 64; m <<= 1) {
            sG += __shfl_xor(sG, m);
            sH += __shfl_xor(sH, m);
        }
        if (lane == 0) {
            disG[r] = 1.f / sqrtf(sG + 1.f);
            disH[r] = (r == 55) ? 0.f : 1.f / sqrtf(sH + 1.f);
        }
    }
    __syncthreads();

    // ---- P3: T64 = disH .* (x @ W1hemi), 4-row register blocking ----
    #pragma unroll 1
    for (int half = 0; half < 2; ++half) {
        const float* W = (half == 0) ? Wl1 : Wr1;
        __syncthreads();
        #pragma unroll 2
        for (int o = tid; o < 1792; o += NT) {         // 112x16 float4; row111=0
            float4 v = make_float4(0.f, 0.f, 0.f, 0.f);
            if (o < 1776) v = ((const float4*)W)[o];
            ((float4*)Wlds)[o] = v;
        }
        __syncthreads();
        const int rlim  = (half == 0) ? 55 : 111;
        const int rbase = (half == 0) ? wv * 4 : 56 + wv * 4;
        float acc[4] = {0,0,0,0};
        int rr[4];
        #pragma unroll
        for (int u = 0; u < 4; ++u) { int r = rbase + u; rr[u] = (r < rlim) ? r : (rlim - 1); }
        #pragma unroll 1
        for (int j4 = 0; j4 < 28; ++j4) {
            float w0 = Wlds[(4 * j4 + 0) * 64 + lane];
            float w1 = Wlds[(4 * j4 + 1) * 64 + lane];
            float w2 = Wlds[(4 * j4 + 2) * 64 + lane];
            float w3 = Wlds[(4 * j4 + 3) * 64 + lane];
            #pragma unroll
            for (int u = 0; u < 4; ++u) {
                const float4 xv = *(const float4*)&Xs[rr[u] * NR + 4 * j4];  // broadcast
                acc[u] += xv.x * w0 + xv.y * w1 + xv.z * w2 + xv.w * w3;
            }
        }
        #pragma unroll
        for (int u = 0; u < 4; ++u) {
            int r = rbase + u;
            if (r < rlim) T64[r * 64 + lane] = disH[r] * acc[u];
        }
    }
    __syncthreads();

    // ---- P4 prologue: stage Wl2|Wr2 + Wg1 (Xs dead); re-zero H1 row 55; fence ----
    #pragma unroll 2
    for (int o = tid; o < 1280; o += NT) { W2s[o] = Wl2[o]; W2s[1280 + o] = Wr2[o]; }
    if (tid < 400) Wg1s[tid] = Wg1[tid];
    if (tid >= 448 && tid < 512) H1[55 * 64 + (tid - 448)] = 0.f;
    __syncthreads();

    // ---- P4: H1 = lrelu(disH*(Ag_block @ T64 + self) + b1), 4-row blocking ----
    #pragma unroll 1
    for (int half = 0; half < 2; ++half) {
        const int  rbase = half == 0 ? wv * 4 : 56 + wv * 4;
        const int  rlim  = half == 0 ? 55 : 111;
        const int  jb    = half == 0 ? 0 : 56;
        const float* bb  = half == 0 ? bl1 : br1;
        float acc[4] = {0,0,0,0};
        int rr[4];
        #pragma unroll
        for (int u = 0; u < 4; ++u) { int r = rbase + u; rr[u] = (r < rlim) ? r : (rlim - 1); }
        #pragma unroll 2
        for (int j4 = 0; j4 < 14; ++j4) {
            float t0 = T64[(jb + 4 * j4 + 0) * 64 + lane];
            float t1 = T64[(jb + 4 * j4 + 1) * 64 + lane];
            float t2 = T64[(jb + 4 * j4 + 2) * 64 + lane];
            float t3 = T64[(jb + 4 * j4 + 3) * 64 + lane];
            #pragma unroll
            for (int u = 0; u < 4; ++u) {
                const float4 a4 = *(const float4*)&Ag[rr[u] * NR + jb + 4 * j4];
                acc[u] += a4.x * t0 + a4.y * t1 + a4.z * t2 + a4.w * t3;
            }
        }
        float bv = bb[lane];
        #pragma unroll
        for (int u = 0; u < 4; ++u) {
            int r = rbase + u;
            if (r < rlim && r != 55)
                H1[r * 64 + lane] = lrelu(disH[r] * (acc[u] + T64[r * 64 + lane]) + bv);
        }
    }
    __syncthreads();

    // ---- P5: T20x = disH .* (H1 @ W2hemi)  (dual accumulators) ----
    for (int o = tid; o < 2240; o += NT) {
        int i = o / 20, c = o % 20;
        if (i == 111) { T20x[o] = 0.f; continue; }
        const float* W2 = (i < 56) ? W2s : (W2s + 1280);
        const float4* h4 = (const float4*)(H1 + i * 64);
        float acc0 = 0.f, acc1 = 0.f;
        #pragma unroll 2
        for (int k4 = 0; k4 < 16; k4 += 2) {
            float4 h0 = h4[k4];
            acc0 += h0.x * W2[(4 * k4 + 0) * 20 + c]
                  + h0.y * W2[(4 * k4 + 1) * 20 + c]
                  + h0.z * W2[(4 * k4 + 2) * 20 + c]
                  + h0.w * W2[(4 * k4 + 3) * 20 + c];
            float4 h1 = h4[k4 + 1];
            acc1 += h1.x * W2[(4 * k4 + 4) * 20 + c]
                  + h1.y * W2[(4 * k4 + 5) * 20 + c]
                  + h1.z * W2[(4 * k4 + 6) * 20 + c]
                  + h1.w * W2[(4 * k4 + 7) * 20 + c];
        }
        T20x[o] = disH[i] * (acc0 + acc1);
    }
    __syncthreads();

    // ---- P6: H2 = lrelu(disH*(Ag_block @ T20x + self) + b2)  (dual acc) ----
    for (int o = tid; o < 2220; o += NT) {
        int i = o / 20, c = o % 20;
        if (i == 55) { H2[o] = 0.f; continue; }
        int jb = (i < 56) ? 0 : 56;
        float acc0 = 0.f, acc1 = 0.f;
        #pragma unroll 2
        for (int j4 = 0; j4 < 14; j4 += 2) {
            const float4 a4 = *(const float4*)&Ag[i * NR + jb + 4 * j4];
            acc0 += a4.x * T20x[(jb + 4 * j4 + 0) * 20 + c]
                  + a4.y * T20x[(jb + 4 * j4 + 1) * 20 + c]
                  + a4.z * T20x[(jb + 4 * j4 + 2) * 20 + c]
                  + a4.w * T20x[(jb + 4 * j4 + 3) * 20 + c];
            const float4 b4 = *(const float4*)&Ag[i * NR + jb + 4 * j4 + 4];
            acc1 += b4.x * T20x[(jb + 4 * j4 + 4) * 20 + c]
                  + b4.y * T20x[(jb + 4 * j4 + 5) * 20 + c]
                  + b4.z * T20x[(jb + 4 * j4 + 6) * 20 + c]
                  + b4.w * T20x[(jb + 4 * j4 + 7) * 20 + c];
        }
        float bv = (i < 56) ? bl2[c] : br2[c];
        H2[o] = lrelu(disH[i] * (acc0 + acc1 + T20x[i * 20 + c]) + bv);
    }
    __syncthreads();

    // ---- P7: T20g = disG .* (H2 @ Wg1s)  (LDS weights, dual acc) ----
    for (int o = tid; o < 2240; o += NT) {
        int i = o / 20, c = o % 20;
        if (i == 111) { T20x[o] = 0.f; continue; }
        float acc0 = 0.f, acc1 = 0.f;
        #pragma unroll 2
        for (int k = 0; k < 20; k += 2) {
            acc0 += H2[i * 20 + k]     * Wg1s[k * 20 + c];
            acc1 += H2[i * 20 + k + 1] * Wg1s[(k + 1) * 20 + c];
        }
        T20x[o] = disG[i] * (acc0 + acc1);
    }
    __syncthreads();

    // ---- P8: H2g = lrelu(disG*(Ag @ T20g + self) + bg1)  (dual acc) ----
    for (int o = tid; o < 2220; o += NT) {
        int i = o / 20, c = o % 20;
        float acc0 = 0.f, acc1 = 0.f;
        #pragma unroll 2
        for (int j4 = 0; j4 < 28; j4 += 2) {
            const float4 a4 = *(const float4*)&Ag[i * NR + 4 * j4];
            acc0 += a4.x * T20x[(4 * j4 + 0) * 20 + c]
                  + a4.y * T20x[(4 * j4 + 1) * 20 + c]
                  + a4.z * T20x[(4 * j4 + 2) * 20 + c]
                  + a4.w * T20x[(4 * j4 + 3) * 20 + c];
            const float4 b4 = *(const float4*)&Ag[i * NR + 4 * j4 + 4];
            acc1 += b4.x * T20x[(4 * j4 + 4) * 20 + c]
                  + b4.y * T20x[(4 * j4 + 5) * 20 + c]
                  + b4.z * T20x[(4 * j4 + 6) * 20 + c]
                  + b4.w * T20x[(4 * j4 + 7) * 20 + c];
        }
        H2g[o] = lrelu(disG[i] * (acc0 + acc1 + T20x[i * 20 + c]) + bg1[c]);
    }
    __syncthreads();

    // ---- P9a: u = H2g.Wrel ; v = H2g.Wroot ----
    if (tid < 112) {
        if (tid == 111) { disC[111] = 0.f; scoreS[111] = 0.f; }
        else {
            float uu = 0.f, vv = 0.f;
            #pragma unroll 4
            for (int c = 0; c < 20; ++c) {
                float h = H2g[tid * 20 + c];
                uu += h * Wrel[c];
                vv += h * Wroot[c];
            }
            disC[tid] = uu; scoreS[tid] = vv;
        }
    }
    __syncthreads();

    // ---- P9b: score[i] = tanh(Ag row i . u + v[i] + brel) ----
    {
        float brel0 = brel[0];
        #pragma unroll 1
        for (int k = 0; k < 7; ++k) {
            int r = wv + 16 * k;
            if (r >= N) continue;
            float p = Ag[r * NR + lane] * disC[lane];
            if (lane < 48) p += Ag[r * NR + 64 + lane] * disC[64 + lane];
            #pragma unroll
            for (int m = 1; m < 64; m <<= 1) p += __shfl_xor(p, m);
            if (lane == 0) scoreS[r] = tanhf(p + scoreS[r] + brel0);
        }
    }
    __syncthreads();

    // ---- P10: rank, perm, sp ; zero Ap ----
    if (tid < N) {
        float si = scoreS[tid];
        int oi = d_P2O[tid];
        int r = 0;
        #pragma unroll 4
        for (int j = 0; j < N; ++j) {
            float sj = scoreS[j];
            r += (sj > si || (sj == si && d_P2O[j] < oi)) ? 1 : 0;
        }
        mapRank[tid] = (r < KP) ? r : -1;
        if (r < KP) permSh[r] = tid;
    }
    if (tid == N) mapRank[111] = -1;
    for (int o = tid; o < KP * APs; o += NT) Ap[o] = 0.f;
    __syncthreads();
    if (tid < N && mapRank[tid] >= 0) {
        int oi = d_P2O[tid], pos = 0;
        #pragma unroll 4
        for (int j = 0; j < N; ++j) pos += (mapRank[j] >= 0 && d_P2O[j] < oi) ? 1 : 0;
        spSh[pos] = tid;
    }
    __syncthreads();
    // ---- P11: scatter filtered adjacency (rank space) ----
    #pragma unroll 2
    for (int e = tid; e < NE; e += NT) {
        int sr = o2rS[edge_index[e]];
        int tr = o2rS[edge_index[NE + e]];
        int ms = mapRank[sr], mt = mapRank[tr];
        if (ms >= 0 && mt >= 0 && ms != mt) atomicAdd(&Ap[mt * APs + ms], 1.f);
    }
    __syncthreads();

    // ---- P12: disC from column sums of Ap ----
    if (tid < APs) {
        if (tid >= KP) disC[tid] = 0.f;
        else {
            float d0 = 0.f, d1 = 0.f;
            #pragma unroll 4
            for (int a = 0; a < KP; a += 2) {
                d0 += Ap[a * APs + tid];
                d1 += Ap[(a + 1) * APs + tid];
            }
            float d = d0 + d1;
            disC[tid] = (d > 0.f) ? 1.f / sqrtf(d) : 0.f;
        }
    }
    __syncthreads();

    // ---- P13: TC[b] = disC[b]*h2[node b]; stage Wcs; zero TC2 tail rows ----
    for (int o = tid; o < APs * 20; o += NT) {
        int bq = o / 20, c = o % 20;
        TC[o] = disC[bq] * H2g[o2rS[bq] * 20 + c];
    }
    #pragma unroll 2
    for (int o = tid; o < 1120; o += NT) {
        Wcs[o] = Wc0[o]; Wcs[1120 + o] = Wc1[o]; Wcs[2240 + o] = Wc2[o];
    }
    if (tid < 80) TC2[2000 + tid] = 0.f;   // rows 100..103 for P15b float4 reads
    __syncthreads();

    // ---- P14: Tx1 = -disC*(Ap@TC); TC2 = disC*Tx1 (P15a fused; dual acc) ----
    for (int o = tid; o < KP * 20; o += NT) {
        int a = o / 20, c = o % 20;
        float acc0 = 0.f, acc1 = 0.f;
        #pragma unroll 2
        for (int j4 = 0; j4 < 26; j4 += 2) {
            const float4 a4 = *(const float4*)&Ap[a * APs + 4 * j4];
            acc0 += a4.x * TC[(4 * j4 + 0) * 20 + c]
                  + a4.y * TC[(4 * j4 + 1) * 20 + c]
                  + a4.z * TC[(4 * j4 + 2) * 20 + c]
                  + a4.w * TC[(4 * j4 + 3) * 20 + c];
            const float4 b4 = *(const float4*)&Ap[a * APs + 4 * j4 + 4];
            acc1 += b4.x * TC[(4 * j4 + 4) * 20 + c]
                  + b4.y * TC[(4 * j4 + 5) * 20 + c]
                  + b4.z * TC[(4 * j4 + 6) * 20 + c]
                  + b4.w * TC[(4 * j4 + 7) * 20 + c];
        }
        float t = -disC[a] * (acc0 + acc1);
        Tx1[o] = t;
        TC2[o] = disC[a] * t;
    }
    __syncthreads();

    // ---- P15b: Tx2 = -2*disC*(Ap@TC2) - h2[node a]  (dual acc) ----
    for (int o = tid; o < KP * 20; o += NT) {
        int a = o / 20, c = o % 20;
        float acc0 = 0.f, acc1 = 0.f;
        #pragma unroll 2
        for (int j4 = 0; j4 < 26; j4 += 2) {
            const float4 a4 = *(const float4*)&Ap[a * APs + 4 * j4];
            acc0 += a4.x * TC2[(4 * j4 + 0) * 20 + c]
                  + a4.y * TC2[(4 * j4 + 1) * 20 + c]
                  + a4.z * TC2[(4 * j4 + 2) * 20 + c]
                  + a4.w * TC2[(4 * j4 + 3) * 20 + c];
            const float4 b4 = *(const float4*)&Ap[a * APs + 4 * j4 + 4];
            acc1 += b4.x * TC2[(4 * j4 + 4) * 20 + c]
                  + b4.y * TC2[(4 * j4 + 5) * 20 + c]
                  + b4.z * TC2[(4 * j4 + 6) * 20 + c]
                  + b4.w * TC2[(4 * j4 + 7) * 20 + c];
        }
        Tx2[o] = -2.f * disC[a] * (acc0 + acc1) - H2g[o2rS[a] * 20 + c];
    }
    __syncthreads();

    // ---- P16: assignment logits — 7-row blocking, single pass (16x7=112) ----
    {
        float bcv = (lane < CA) ? bc[lane] : 0.f;
        const int base = wv * 7;
        float acc[7] = {0,0,0,0,0,0,0};
        int ho[7], txo[7], in7[7];
        #pragma unroll
        for (int u = 0; u < 7; ++u) {
            int i = base + u;
            int ic = (i < N) ? i : (N - 1);
            ho[u]  = o2rS[ic] * 20;
            in7[u] = (ic < KP) ? 1 : 0;
            txo[u] = ((ic < KP) ? ic : 0) * 20;
        }
        #pragma unroll 1
        for (int k = 0; k < 20; ++k) {
            float w0 = Wcs[k * CA + lane];
            float w1 = Wcs[1120 + k * CA + lane];
            float w2 = Wcs[2240 + k * CA + lane];
            #pragma unroll
            for (int u = 0; u < 7; ++u) {
                float h  = H2g[ho[u] + k];
                float t1 = in7[u] ? Tx1[txo[u] + k] : 0.f;
                float t2 = in7[u] ? Tx2[txo[u] + k] : -h;
                acc[u] += h * w0 + t1 * w1 + t2 * w2;
            }
        }
        #pragma unroll
        for (int u = 0; u < 7; ++u) {
            int i = base + u;
            if (i < N && lane < CA) assS[i * CA + lane] = acc[u] + bcv;
        }
    }
    __syncthreads();

    // ---- P16b: double softmax per row (wave/row, butterfly) ----
    #pragma unroll 1
    for (int k = 0; k < 7; ++k) {
        int r = wv + 16 * k;
        if (r >= N) continue;
        float v = (lane < CA) ? assS[r * CA + lane] : -3.4e38f;
        float m = v;
        #pragma unroll
        for (int s = 1; s < 64; s <<= 1) m = fmaxf(m, __shfl_xor(m, s));
        float e = (lane < CA) ? expf(v - m) : 0.f;
        float sum = e;
        #pragma unroll
        for (int s = 1; s < 64; s <<= 1) sum += __shfl_xor(sum, s);
        float p1 = e / sum;
        float m2 = (lane < CA) ? p1 : -3.4e38f;
        #pragma unroll
        for (int s = 1; s < 64; s <<= 1) m2 = fmaxf(m2, __shfl_xor(m2, s));
        float e2 = (lane < CA) ? expf(p1 - m2) : 0.f;
        float sum2 = e2;
        #pragma unroll
        for (int s = 1; s < 64; s <<= 1) sum2 += __shfl_xor(sum2, s);
        if (lane < CA) {
            assS[r * CA + lane] = p1;
            s2S[r * CA + lane]  = e2 / sum2;
        }
    }
    __syncthreads();

    // ---- P17: Hc = s2^T @ h2 (dual acc) ----
    for (int o = tid; o < CA * 20; o += NT) {
        int q = o / 20, c = o % 20;
        float a0 = 0.f, a1 = 0.f;
        #pragma unroll 2
        for (int r = 0; r < 110; r += 2) {
            a0 += s2S[d_P2O[r] * CA + q]     * H2g[r * 20 + c];
            a1 += s2S[d_P2O[r + 1] * CA + q] * H2g[(r + 1) * 20 + c];
        }
        a0 += s2S[d_P2O[110] * CA + q] * H2g[110 * 20 + c];
        HcS[o] = a0 + a1;
    }
    __syncthreads();

    // ---- P18: out = pooled + inter @ Hc (dual acc) ----
    for (int o = tid; o < KP * 20; o += NT) {
        int k = o / 20, c = o % 20;
        int rp = permSh[k];
        float v = H2g[rp * 20 + c] * scoreS[rp];
        int oi = d_P2O[spSh[k]];
        if (oi < 110) {
            float a0 = 0.f, a1 = 0.f;
            #pragma unroll 4
            for (int q = 0; q < CA; q += 2) {
                a0 += assS[oi * CA + q]     * HcS[q * 20 + c];
                a1 += assS[oi * CA + q + 1] * HcS[(q + 1) * 20 + c];
            }
            v += a0 + a1;
        }
        out[(size_t)b * (KP * 20) + o] = v;
    }
}

extern "C" void kernel_launch(void* const* d_in, const int* in_sizes, int n_in,
                              void* d_out, int out_size, void* d_ws, size_t ws_size,
                              hipStream_t stream) {
    const float* features   = (const float*)d_in[0];
    const float* edge_attr  = (const float*)d_in[1];
    // d_in[2] = adj (unused by reference)
    const int*   edge_index = (const int*)d_in[3];
    const float* Wl1 = (const float*)d_in[4];
    const float* bl1 = (const float*)d_in[5];
    const float* Wr1 = (const float*)d_in[6];
    const float* br1 = (const float*)d_in[7];
    const float* Wl2 = (const float*)d_in[8];
    const float* bl2 = (const float*)d_in[9];
    const float* Wr2 = (const float*)d_in[10];
    const float* br2 = (const float*)d_in[11];
    const float* Wg1 = (const float*)d_in[12];
    const float* bg1 = (const float*)d_in[13];
    const float* Wrel = (const float*)d_in[14];
    const float* brel = (const float*)d_in[15];
    const float* Wroot = (const float*)d_in[16];
    const float* Wc0 = (const float*)d_in[17];
    const float* Wc1 = (const float*)d_in[18];
    const float* Wc2 = (const float*)d_in[19];
    const float* bc  = (const float*)d_in[20];
    float* out = (float*)d_out;

    int B = in_sizes[0] / (N * N);
    brain_fused<<<dim3(B), dim3(NT), 0, stream>>>(
        features, edge_attr, edge_index,
        Wl1, bl1, Wr1, br1, Wl2, bl2, Wr2, br2, Wg1, bg1,
        Wrel, brel, Wroot, Wc0, Wc1, Wc2, bc, out);
}

// Round 16
// 822.008 us; speedup vs baseline: 1.1504x; 1.1504x over previous
//
#include <hip/hip_runtime.h>
#include <math.h>

#define N    111
#define NR   112      // padded row/col stride for Ag and Xs
#define NE   4000
#define KP   100
#define APs  104      // Ap col stride
#define CA   56
#define NT   1024     // 16 waves = 4/SIMD; occupancy cap for 160KB-LDS blocks (R14)

// permuted row -> original node id. rows 0..54 LEFT, 55 = node82, 56..110 RIGHT, 111 pad
__device__ __constant__ int d_P2O[112] = {
  6,5,55,1,98,71,73,77,63,96,79,15,104,4,25,23,41,43,45,17,61,65,59,57,86,21,
  35,37,39,94,110,3,69,81,84,100,102,106,47,27,75,2,67,19,49,31,33,108,51,53,
  88,90,92,29,0,
  82,
  13,12,54,8,97,70,72,76,62,95,78,14,103,11,24,22,40,42,44,16,60,64,58,56,85,
  20,34,36,38,93,109,10,68,80,83,99,101,105,46,26,74,9,66,18,48,30,32,107,50,
  52,87,89,91,28,7,
  111};

// flat LDS float pool offsets (floats)
#define OFF_A 0        // Ag 112x112=12544 -> Ap 100x104 -> assS 111x56 (6216) + HcS 56x20 (@+6216)
#define OFF_B 12544    // Xs 111x112 (P3) -> {W2s 2x1280 | Wg1s 400 @+2560} -> {TC|Tx1|Tx2|TC2} -> s2S 111x56
#define OFF_C 24976    // T64 112x64=7168 -> T20x 112x20=2240 -> Wcs 3x1120 (P16)
#define OFF_D 32144    // H1 112x64=7168 (P3: Wlds stage, row111=0) -> {H2 | H2g @ +2240}
#define FSZ   39312

__device__ __forceinline__ float lrelu(float h) { return h > 0.f ? h : 0.01f * h; }

// R11: capped unrolls (no spills). R12: 7-row blocking. R13 transpose REVERTED
// (bank conflicts). R14: NT=1024 (occupancy cap 48%). R15 dual-acc: neutral.
// R16: c-quad output tiling — every 20-wide phase computes float4 of 4 adjacent
// c columns per thread, turning scalar operand reads into broadcast float4
// reads (LDS-pipe issue cut 2-4x; layouts stay row-major = conflict-free).
__global__ __launch_bounds__(NT, 1)
void brain_fused(const float* __restrict__ features,
                 const float* __restrict__ edge_attr,
                 const int*   __restrict__ edge_index,
                 const float* __restrict__ Wl1, const float* __restrict__ bl1,
                 const float* __restrict__ Wr1, const float* __restrict__ br1,
                 const float* __restrict__ Wl2, const float* __restrict__ bl2,
                 const float* __restrict__ Wr2, const float* __restrict__ br2,
                 const float* __restrict__ Wg1, const float* __restrict__ bg1,
                 const float* __restrict__ Wrel, const float* __restrict__ brel,
                 const float* __restrict__ Wroot,
                 const float* __restrict__ Wc0, const float* __restrict__ Wc1,
                 const float* __restrict__ Wc2, const float* __restrict__ bc,
                 float* __restrict__ out)
{
    __shared__ __align__(16) float F[FSZ];
    __shared__ float disH[112], disG[112], disC[112], scoreS[112];
    __shared__ int o2rS[112], mapRank[112], permSh[KP], spSh[KP];

    float* Ag   = F + OFF_A;            // 112x112
    float* Ap   = F + OFF_A;            // 100x104
    float* assS = F + OFF_A;            // 111x56
    float* HcS  = F + OFF_A + 6216;     // 56x20
    float* Xs   = F + OFF_B;            // 111x112 permuted rows, col111=0 (P3)
    float* W2s  = F + OFF_B;            // Wl2|Wr2 (2x1280) during P5
    float* Wg1s = F + OFF_B + 2560;     // 400 floats (P7)
    float* TC   = F + OFF_B;            // 104x20
    float* Tx1  = F + OFF_B + 2080;     // 100x20
    float* Tx2  = F + OFF_B + 4080;     // 100x20
    float* TC2  = F + OFF_B + 6160;     // 104x20 (disC*Tx1, written by P14)
    float* s2S  = F + OFF_B;            // 111x56 (after P16b; TC2 dead by then)
    float* T64  = F + OFF_C;            // 112x64
    float* T20x = F + OFF_C;            // 112x20
    float* Wcs  = F + OFF_C;            // Wc0|Wc1|Wc2 3x1120 (P16)
    float* H1   = F + OFF_D;            // 112x64
    float* Wlds = F + OFF_D;            // 112x64 W1 stage during P3 (row111=0)
    float* H2   = F + OFF_D;            // 112x20
    float* H2g  = F + OFF_D + 2240;     // 112x20

    const int b    = blockIdx.x;
    const int tid  = threadIdx.x;
    const int lane = tid & 63;
    const int wv   = tid >> 6;          // 0..15
    const float* x = features + (size_t)b * (N * N);

    // ---- P0: zero Ag, T64; build orig->row map ----
    for (int o = tid; o < 12544; o += NT) Ag[o] = 0.f;
    for (int o = tid; o < 7168;  o += NT) T64[o] = 0.f;
    if (tid < 112) o2rS[d_P2O[tid]] = tid;
    __syncthreads();

    // ---- P1a: scatter edges into Ag[t,s] (permuted) ----
    #pragma unroll 2
    for (int e = tid; e < NE; e += NT) {
        int s = o2rS[edge_index[e]];
        int t = o2rS[edge_index[NE + e]];
        atomicAdd(&Ag[t * NR + s], edge_attr[(size_t)b * NE + e]);
    }
    __syncthreads();

    // ---- P1b: stage x, permuted rows, stride 112, col111=0 ----
    #pragma unroll 2
    for (int o = tid; o < N * NR; o += NT) {
        int r = o / NR, cc = o % NR;
        Xs[o] = (cc < N) ? x[d_P2O[r] * N + cc] : 0.f;
    }
    __syncthreads();

    // ---- P2: degrees (wave/row over 16 waves, butterfly) ----
    #pragma unroll 1
    for (int k = 0; k < 7; ++k) {
        int r = wv + 16 * k;
        if (r >= 112) continue;
        if (r == 111) { if (lane == 0) { disH[111] = 0.f; disG[111] = 0.f; } continue; }
        float a0 = Ag[r * NR + lane];
        float a1 = (lane < 48) ? Ag[r * NR + 64 + lane] : 0.f;
        float sG = a0 + a1;
        float sH;
        if (r < 55)       sH = (lane < 55) ? a0 : 0.f;
        else if (r >= 56) sH = ((lane >= 56) ? a0 : 0.f) + ((lane < 47) ? a1 : 0.f);
        else              sH = 0.f;
        #pragma unroll
        for (int m = 1; m < 64; m <<= 1) {
            sG += __shfl_xor(sG, m);
            sH += __shfl_xor(sH, m);
        }
        if (lane == 0) {
            disG[r] = 1.f / sqrtf(sG + 1.f);
            disH[r] = (r == 55) ? 0.f : 1.f / sqrtf(sH + 1.f);
        }
    }
    __syncthreads();

    // ---- P3: T64 = disH .* (x @ W1hemi), 4-row register blocking ----
    #pragma unroll 1
    for (int half = 0; half < 2; ++half) {
        const float* W = (half == 0) ? Wl1 : Wr1;
        __syncthreads();
        #pragma unroll 2
        for (int o = tid; o < 1792; o += NT) {         // 112x16 float4; row111=0
            float4 v = make_float4(0.f, 0.f, 0.f, 0.f);
            if (o < 1776) v = ((const float4*)W)[o];
            ((float4*)Wlds)[o] = v;
        }
        __syncthreads();
        const int rlim  = (half == 0) ? 55 : 111;
        const int rbase = (half == 0) ? wv * 4 : 56 + wv * 4;
        float acc[4] = {0,0,0,0};
        int rr[4];
        #pragma unroll
        for (int u = 0; u < 4; ++u) { int r = rbase + u; rr[u] = (r < rlim) ? r : (rlim - 1); }
        #pragma unroll 1
        for (int j4 = 0; j4 < 28; ++j4) {
            float w0 = Wlds[(4 * j4 + 0) * 64 + lane];
            float w1 = Wlds[(4 * j4 + 1) * 64 + lane];
            float w2 = Wlds[(4 * j4 + 2) * 64 + lane];
            float w3 = Wlds[(4 * j4 + 3) * 64 + lane];
            #pragma unroll
            for (int u = 0; u < 4; ++u) {
                const float4 xv = *(const float4*)&Xs[rr[u] * NR + 4 * j4];  // broadcast
                acc[u] += xv.x * w0 + xv.y * w1 + xv.z * w2 + xv.w * w3;
            }
        }
        #pragma unroll
        for (int u = 0; u < 4; ++u) {
            int r = rbase + u;
            if (r < rlim) T64[r * 64 + lane] = disH[r] * acc[u];
        }
    }
    __syncthreads();

    // ---- P4 prologue: stage Wl2|Wr2 + Wg1 (Xs dead); re-zero H1 row 55; fence ----
    #pragma unroll 2
    for (int o = tid; o < 1280; o += NT) { W2s[o] = Wl2[o]; W2s[1280 + o] = Wr2[o]; }
    if (tid < 400) Wg1s[tid] = Wg1[tid];
    if (tid >= 448 && tid < 512) H1[55 * 64 + (tid - 448)] = 0.f;
    __syncthreads();

    // ---- P4: H1 = lrelu(disH*(Ag_block @ T64 + self) + b1), 4-row blocking ----
    #pragma unroll 1
    for (int half = 0; half < 2; ++half) {
        const int  rbase = half == 0 ? wv * 4 : 56 + wv * 4;
        const int  rlim  = half == 0 ? 55 : 111;
        const int  jb    = half == 0 ? 0 : 56;
        const float* bb  = half == 0 ? bl1 : br1;
        float acc[4] = {0,0,0,0};
        int rr[4];
        #pragma unroll
        for (int u = 0; u < 4; ++u) { int r = rbase + u; rr[u] = (r < rlim) ? r : (rlim - 1); }
        #pragma unroll 2
        for (int j4 = 0; j4 < 14; ++j4) {
            float t0 = T64[(jb + 4 * j4 + 0) * 64 + lane];
            float t1 = T64[(jb + 4 * j4 + 1) * 64 + lane];
            float t2 = T64[(jb + 4 * j4 + 2) * 64 + lane];
            float t3 = T64[(jb + 4 * j4 + 3) * 64 + lane];
            #pragma unroll
            for (int u = 0; u < 4; ++u) {
                const float4 a4 = *(const float4*)&Ag[rr[u] * NR + jb + 4 * j4];
                acc[u] += a4.x * t0 + a4.y * t1 + a4.z * t2 + a4.w * t3;
            }
        }
        float bv = bb[lane];
        #pragma unroll
        for (int u = 0; u < 4; ++u) {
            int r = rbase + u;
            if (r < rlim && r != 55)
                H1[r * 64 + lane] = lrelu(disH[r] * (acc[u] + T64[r * 64 + lane]) + bv);
        }
    }
    __syncthreads();

    // ---- P5: T20x quad = disH .* (H1 @ W2hemi) — c-quad tiling (560 items) ----
    for (int o = tid; o < 560; o += NT) {
        int i = o / 5, c0 = (o % 5) * 4;
        if (i == 111) { *(float4*)&T20x[i * 20 + c0] = make_float4(0.f,0.f,0.f,0.f); continue; }
        const float* W2 = (i < 56) ? W2s : (W2s + 1280);
        const float4* h4 = (const float4*)(H1 + i * 64);
        float4 acc = make_float4(0.f,0.f,0.f,0.f);
        #pragma unroll 2
        for (int k4 = 0; k4 < 16; ++k4) {
            float4 h = h4[k4];
            float4 w0 = *(const float4*)&W2[(4 * k4 + 0) * 20 + c0];
            float4 w1 = *(const float4*)&W2[(4 * k4 + 1) * 20 + c0];
            float4 w2 = *(const float4*)&W2[(4 * k4 + 2) * 20 + c0];
            float4 w3 = *(const float4*)&W2[(4 * k4 + 3) * 20 + c0];
            acc.x += h.x * w0.x + h.y * w1.x + h.z * w2.x + h.w * w3.x;
            acc.y += h.x * w0.y + h.y * w1.y + h.z * w2.y + h.w * w3.y;
            acc.z += h.x * w0.z + h.y * w1.z + h.z * w2.z + h.w * w3.z;
            acc.w += h.x * w0.w + h.y * w1.w + h.z * w2.w + h.w * w3.w;
        }
        float d = disH[i];
        *(float4*)&T20x[i * 20 + c0] = make_float4(d*acc.x, d*acc.y, d*acc.z, d*acc.w);
    }
    __syncthreads();

    // ---- P6: H2 quad = lrelu(disH*(Ag_block @ T20x + self) + b2) — 555 items ----
    for (int o = tid; o < 555; o += NT) {
        int i = o / 5, c0 = (o % 5) * 4;
        if (i == 55) { *(float4*)&H2[i * 20 + c0] = make_float4(0.f,0.f,0.f,0.f); continue; }
        int jb = (i < 56) ? 0 : 56;
        float4 acc = make_float4(0.f,0.f,0.f,0.f);
        #pragma unroll 2
        for (int j4 = 0; j4 < 14; ++j4) {
            float4 a  = *(const float4*)&Ag[i * NR + jb + 4 * j4];
            float4 t0 = *(const float4*)&T20x[(jb + 4 * j4 + 0) * 20 + c0];
            float4 t1 = *(const float4*)&T20x[(jb + 4 * j4 + 1) * 20 + c0];
            float4 t2 = *(const float4*)&T20x[(jb + 4 * j4 + 2) * 20 + c0];
            float4 t3 = *(const float4*)&T20x[(jb + 4 * j4 + 3) * 20 + c0];
            acc.x += a.x * t0.x + a.y * t1.x + a.z * t2.x + a.w * t3.x;
            acc.y += a.x * t0.y + a.y * t1.y + a.z * t2.y + a.w * t3.y;
            acc.z += a.x * t0.z + a.y * t1.z + a.z * t2.z + a.w * t3.z;
            acc.w += a.x * t0.w + a.y * t1.w + a.z * t2.w + a.w * t3.w;
        }
        float4 self = *(const float4*)&T20x[i * 20 + c0];
        float4 bv = *(const float4*)&((i < 56) ? bl2 : br2)[c0];
        float dh = disH[i];
        float4 r;
        r.x = lrelu(dh * (acc.x + self.x) + bv.x);
        r.y = lrelu(dh * (acc.y + self.y) + bv.y);
        r.z = lrelu(dh * (acc.z + self.z) + bv.z);
        r.w = lrelu(dh * (acc.w + self.w) + bv.w);
        *(float4*)&H2[i * 20 + c0] = r;
    }
    __syncthreads();

    // ---- P7: T20x quad = disG .* (H2 @ Wg1s) — 560 items ----
    for (int o = tid; o < 560; o += NT) {
        int i = o / 5, c0 = (o % 5) * 4;
        if (i == 111) { *(float4*)&T20x[i * 20 + c0] = make_float4(0.f,0.f,0.f,0.f); continue; }
        float4 acc = make_float4(0.f,0.f,0.f,0.f);
        #pragma unroll 4
        for (int k = 0; k < 20; ++k) {
            float h = H2[i * 20 + k];
            float4 w = *(const float4*)&Wg1s[k * 20 + c0];
            acc.x += h * w.x; acc.y += h * w.y; acc.z += h * w.z; acc.w += h * w.w;
        }
        float d = disG[i];
        *(float4*)&T20x[i * 20 + c0] = make_float4(d*acc.x, d*acc.y, d*acc.z, d*acc.w);
    }
    __syncthreads();

    // ---- P8: H2g quad = lrelu(disG*(Ag @ T20x + self) + bg1) — 555 items ----
    for (int o = tid; o < 555; o += NT) {
        int i = o / 5, c0 = (o % 5) * 4;
        float4 acc = make_float4(0.f,0.f,0.f,0.f);
        #pragma unroll 2
        for (int j4 = 0; j4 < 28; ++j4) {
            float4 a  = *(const float4*)&Ag[i * NR + 4 * j4];
            float4 t0 = *(const float4*)&T20x[(4 * j4 + 0) * 20 + c0];
            float4 t1 = *(const float4*)&T20x[(4 * j4 + 1) * 20 + c0];
            float4 t2 = *(const float4*)&T20x[(4 * j4 + 2) * 20 + c0];
            float4 t3 = *(const float4*)&T20x[(4 * j4 + 3) * 20 + c0];
            acc.x += a.x * t0.x + a.y * t1.x + a.z * t2.x + a.w * t3.x;
            acc.y += a.x * t0.y + a.y * t1.y + a.z * t2.y + a.w * t3.y;
            acc.z += a.x * t0.z + a.y * t1.z + a.z * t2.z + a.w * t3.z;
            acc.w += a.x * t0.w + a.y * t1.w + a.z * t2.w + a.w * t3.w;
        }
        float4 self = *(const float4*)&T20x[i * 20 + c0];
        float4 bv = *(const float4*)&bg1[c0];
        float dg = disG[i];
        float4 r;
        r.x = lrelu(dg * (acc.x + self.x) + bv.x);
        r.y = lrelu(dg * (acc.y + self.y) + bv.y);
        r.z = lrelu(dg * (acc.z + self.z) + bv.z);
        r.w = lrelu(dg * (acc.w + self.w) + bv.w);
        *(float4*)&H2g[i * 20 + c0] = r;
    }
    __syncthreads();

    // ---- P9a: u = H2g.Wrel ; v = H2g.Wroot ----
    if (tid < 112) {
        if (tid == 111) { disC[111] = 0.f; scoreS[111] = 0.f; }
        else {
            float uu = 0.f, vv = 0.f;
            #pragma unroll 4
            for (int c = 0; c < 20; ++c) {
                float h = H2g[tid * 20 + c];
                uu += h * Wrel[c];
                vv += h * Wroot[c];
            }
            disC[tid] = uu; scoreS[tid] = vv;
        }
    }
    __syncthreads();

    // ---- P9b: score[i] = tanh(Ag row i . u + v[i] + brel) ----
    {
        float brel0 = brel[0];
        #pragma unroll 1
        for (int k = 0; k < 7; ++k) {
            int r = wv + 16 * k;
            if (r >= N) continue;
            float p = Ag[r * NR + lane] * disC[lane];
            if (lane < 48) p += Ag[r * NR + 64 + lane] * disC[64 + lane];
            #pragma unroll
            for (int m = 1; m < 64; m <<= 1) p += __shfl_xor(p, m);
            if (lane == 0) scoreS[r] = tanhf(p + scoreS[r] + brel0);
        }
    }
    __syncthreads();

    // ---- P10: rank, perm, sp ; zero Ap ----
    if (tid < N) {
        float si = scoreS[tid];
        int oi = d_P2O[tid];
        int r = 0;
        #pragma unroll 4
        for (int j = 0; j < N; ++j) {
            float sj = scoreS[j];
            r += (sj > si || (sj == si && d_P2O[j] < oi)) ? 1 : 0;
        }
        mapRank[tid] = (r < KP) ? r : -1;
        if (r < KP) permSh[r] = tid;
    }
    if (tid == N) mapRank[111] = -1;
    for (int o = tid; o < KP * APs; o += NT) Ap[o] = 0.f;
    __syncthreads();
    if (tid < N && mapRank[tid] >= 0) {
        int oi = d_P2O[tid], pos = 0;
        #pragma unroll 4
        for (int j = 0; j < N; ++j) pos += (mapRank[j] >= 0 && d_P2O[j] < oi) ? 1 : 0;
        spSh[pos] = tid;
    }
    __syncthreads();
    // ---- P11: scatter filtered adjacency (rank space) ----
    #pragma unroll 2
    for (int e = tid; e < NE; e += NT) {
        int sr = o2rS[edge_index[e]];
        int tr = o2rS[edge_index[NE + e]];
        int ms = mapRank[sr], mt = mapRank[tr];
        if (ms >= 0 && mt >= 0 && ms != mt) atomicAdd(&Ap[mt * APs + ms], 1.f);
    }
    __syncthreads();

    // ---- P12: disC from column sums of Ap ----
    if (tid < APs) {
        if (tid >= KP) disC[tid] = 0.f;
        else {
            float d0 = 0.f, d1 = 0.f;
            #pragma unroll 4
            for (int a = 0; a < KP; a += 2) {
                d0 += Ap[a * APs + tid];
                d1 += Ap[(a + 1) * APs + tid];
            }
            float d = d0 + d1;
            disC[tid] = (d > 0.f) ? 1.f / sqrtf(d) : 0.f;
        }
    }
    __syncthreads();

    // ---- P13: TC quad = disC .* h2[node]; stage Wcs; zero TC2 tail ----
    for (int o = tid; o < 520; o += NT) {
        int bq = o / 5, c0 = (o % 5) * 4;
        float4 h = *(const float4*)&H2g[o2rS[bq] * 20 + c0];
        float d = disC[bq];
        *(float4*)&TC[bq * 20 + c0] = make_float4(d*h.x, d*h.y, d*h.z, d*h.w);
    }
    #pragma unroll 2
    for (int o = tid; o < 1120; o += NT) {
        Wcs[o] = Wc0[o]; Wcs[1120 + o] = Wc1[o]; Wcs[2240 + o] = Wc2[o];
    }
    if (tid < 80) TC2[2000 + tid] = 0.f;   // rows 100..103 for P15b float4 reads
    __syncthreads();

    // ---- P14: Tx1 quad = -disC*(Ap@TC); TC2 = disC*Tx1 — 500 items ----
    for (int o = tid; o < 500; o += NT) {
        int a = o / 5, c0 = (o % 5) * 4;
        float4 acc = make_float4(0.f,0.f,0.f,0.f);
        #pragma unroll 2
        for (int j4 = 0; j4 < 26; ++j4) {
            float4 av = *(const float4*)&Ap[a * APs + 4 * j4];
            float4 t0 = *(const float4*)&TC[(4 * j4 + 0) * 20 + c0];
            float4 t1 = *(const float4*)&TC[(4 * j4 + 1) * 20 + c0];
            float4 t2 = *(const float4*)&TC[(4 * j4 + 2) * 20 + c0];
            float4 t3 = *(const float4*)&TC[(4 * j4 + 3) * 20 + c0];
            acc.x += av.x * t0.x + av.y * t1.x + av.z * t2.x + av.w * t3.x;
            acc.y += av.x * t0.y + av.y * t1.y + av.z * t2.y + av.w * t3.y;
            acc.z += av.x * t0.z + av.y * t1.z + av.z * t2.z + av.w * t3.z;
            acc.w += av.x * t0.w + av.y * t1.w + av.z * t2.w + av.w * t3.w;
        }
        float d = disC[a];
        float4 t = make_float4(-d*acc.x, -d*acc.y, -d*acc.z, -d*acc.w);
        *(float4*)&Tx1[a * 20 + c0] = t;
        *(float4*)&TC2[a * 20 + c0] = make_float4(d*t.x, d*t.y, d*t.z, d*t.w);
    }
    __syncthreads();

    // ---- P15b: Tx2 quad = -2*disC*(Ap@TC2) - h2[node] — 500 items ----
    for (int o = tid; o < 500; o += NT) {
        int a = o / 5, c0 = (o % 5) * 4;
        float4 acc = make_float4(0.f,0.f,0.f,0.f);
        #pragma unroll 2
        for (int j4 = 0; j4 < 26; ++j4) {
            float4 av = *(const float4*)&Ap[a * APs + 4 * j4];
            float4 t0 = *(const float4*)&TC2[(4 * j4 + 0) * 20 + c0];
            float4 t1 = *(const float4*)&TC2[(4 * j4 + 1) * 20 + c0];
            float4 t2 = *(const float4*)&TC2[(4 * j4 + 2) * 20 + c0];
            float4 t3 = *(const float4*)&TC2[(4 * j4 + 3) * 20 + c0];
            acc.x += av.x * t0.x + av.y * t1.x + av.z * t2.x + av.w * t3.x;
            acc.y += av.x * t0.y + av.y * t1.y + av.z * t2.y + av.w * t3.y;
            acc.z += av.x * t0.z + av.y * t1.z + av.z * t2.z + av.w * t3.z;
            acc.w += av.x * t0.w + av.y * t1.w + av.z * t2.w + av.w * t3.w;
        }
        float d2 = -2.f * disC[a];
        float4 h = *(const float4*)&H2g[o2rS[a] * 20 + c0];
        *(float4*)&Tx2[a * 20 + c0] =
            make_float4(d2*acc.x - h.x, d2*acc.y - h.y, d2*acc.z - h.z, d2*acc.w - h.w);
    }
    __syncthreads();

    // ---- P16: assignment logits — 7-row blocking, single pass (16x7=112) ----
    {
        float bcv = (lane < CA) ? bc[lane] : 0.f;
        const int base = wv * 7;
        float acc[7] = {0,0,0,0,0,0,0};
        int ho[7], txo[7], in7[7];
        #pragma unroll
        for (int u = 0; u < 7; ++u) {
            int i = base + u;
            int ic = (i < N) ? i : (N - 1);
            ho[u]  = o2rS[ic] * 20;
            in7[u] = (ic < KP) ? 1 : 0;
            txo[u] = ((ic < KP) ? ic : 0) * 20;
        }
        #pragma unroll 1
        for (int k = 0; k < 20; ++k) {
            float w0 = Wcs[k * CA + lane];
            float w1 = Wcs[1120 + k * CA + lane];
            float w2 = Wcs[2240 + k * CA + lane];
            #pragma unroll
            for (int u = 0; u < 7; ++u) {
                float h  = H2g[ho[u] + k];
                float t1 = in7[u] ? Tx1[txo[u] + k] : 0.f;
                float t2 = in7[u] ? Tx2[txo[u] + k] : -h;
                acc[u] += h * w0 + t1 * w1 + t2 * w2;
            }
        }
        #pragma unroll
        for (int u = 0; u < 7; ++u) {
            int i = base + u;
            if (i < N && lane < CA) assS[i * CA + lane] = acc[u] + bcv;
        }
    }
    __syncthreads();

    // ---- P16b: double softmax per row (wave/row, butterfly) ----
    #pragma unroll 1
    for (int k = 0; k < 7; ++k) {
        int r = wv + 16 * k;
        if (r >= N) continue;
        float v = (lane < CA) ? assS[r * CA + lane] : -3.4e38f;
        float m = v;
        #pragma unroll
        for (int s = 1; s < 64; s <<= 1) m = fmaxf(m, __shfl_xor(m, s));
        float e = (lane < CA) ? expf(v - m) : 0.f;
        float sum = e;
        #pragma unroll
        for (int s = 1; s < 64; s <<= 1) sum += __shfl_xor(sum, s);
        float p1 = e / sum;
        float m2 = (lane < CA) ? p1 : -3.4e38f;
        #pragma unroll
        for (int s = 1; s < 64; s <<= 1) m2 = fmaxf(m2, __shfl_xor(m2, s));
        float e2 = (lane < CA) ? expf(p1 - m2) : 0.f;
        float sum2 = e2;
        #pragma unroll
        for (int s = 1; s < 64; s <<= 1) sum2 += __shfl_xor(sum2, s);
        if (lane < CA) {
            assS[r * CA + lane] = p1;
            s2S[r * CA + lane]  = e2 / sum2;
        }
    }
    __syncthreads();

    // ---- P17: Hc quad = s2^T @ h2 — 280 items ----
    for (int o = tid; o < 280; o += NT) {
        int q = o / 5, c0 = (o % 5) * 4;
        float4 acc = make_float4(0.f,0.f,0.f,0.f);
        #pragma unroll 2
        for (int r = 0; r < N; ++r) {
            float s = s2S[d_P2O[r] * CA + q];
            float4 h = *(const float4*)&H2g[r * 20 + c0];
            acc.x += s * h.x; acc.y += s * h.y; acc.z += s * h.z; acc.w += s * h.w;
        }
        *(float4*)&HcS[q * 20 + c0] = acc;
    }
    __syncthreads();

    // ---- P18: out quad = pooled + inter @ Hc — 500 items, float4 global store ----
    for (int o = tid; o < 500; o += NT) {
        int k = o / 5, c0 = (o % 5) * 4;
        int rp = permSh[k];
        float sc = scoreS[rp];
        float4 hq = *(const float4*)&H2g[rp * 20 + c0];
        float4 v = make_float4(sc*hq.x, sc*hq.y, sc*hq.z, sc*hq.w);
        int oi = d_P2O[spSh[k]];
        if (oi < 110) {
            float4 acc = make_float4(0.f,0.f,0.f,0.f);
            #pragma unroll 4
            for (int q = 0; q < CA; ++q) {
                float s = assS[oi * CA + q];
                float4 h = *(const float4*)&HcS[q * 20 + c0];
                acc.x += s * h.x; acc.y += s * h.y; acc.z += s * h.z; acc.w += s * h.w;
            }
            v.x += acc.x; v.y += acc.y; v.z += acc.z; v.w += acc.w;
        }
        *(float4*)&out[(size_t)b * (KP * 20) + k * 20 + c0] = v;
    }
}

extern "C" void kernel_launch(void* const* d_in, const int* in_sizes, int n_in,
                              void* d_out, int out_size, void* d_ws, size_t ws_size,
                              hipStream_t stream) {
    const float* features   = (const float*)d_in[0];
    const float* edge_attr  = (const float*)d_in[1];
    // d_in[2] = adj (unused by reference)
    const int*   edge_index = (const int*)d_in[3];
    const float* Wl1 = (const float*)d_in[4];
    const float* bl1 = (const float*)d_in[5];
    const float* Wr1 = (const float*)d_in[6];
    const float* br1 = (const float*)d_in[7];
    const float* Wl2 = (const float*)d_in[8];
    const float* bl2 = (const float*)d_in[9];
    const float* Wr2 = (const float*)d_in[10];
    const float* br2 = (const float*)d_in[11];
    const float* Wg1 = (const float*)d_in[12];
    const float* bg1 = (const float*)d_in[13];
    const float* Wrel = (const float*)d_in[14];
    const float* brel = (const float*)d_in[15];
    const float* Wroot = (const float*)d_in[16];
    const float* Wc0 = (const float*)d_in[17];
    const float* Wc1 = (const float*)d_in[18];
    const float* Wc2 = (const float*)d_in[19];
    const float* bc  = (const float*)d_in[20];
    float* out = (float*)d_out;

    int B = in_sizes[0] / (N * N);
    brain_fused<<<dim3(B), dim3(NT), 0, stream>>>(
        features, edge_attr, edge_index,
        Wl1, bl1, Wr1, br1, Wl2, bl2, Wr2, br2, Wg1, bg1,
        Wrel, brel, Wroot, Wc0, Wc1, Wc2, bc, out);
}

// Round 17
// 761.472 us; speedup vs baseline: 1.2419x; 1.0795x over previous
//
#include <hip/hip_runtime.h>
#include <math.h>

#define N    111
#define NR   112      // padded row/col stride for Ag and Xs
#define NE   4000
#define KP   100
#define APs  104      // Ap col stride
#define CA   56
#define NT   1024     // 16 waves = 4/SIMD; occupancy cap for 160KB-LDS blocks (R14)

// permuted row -> original node id. rows 0..54 LEFT, 55 = node82, 56..110 RIGHT, 111 pad
__device__ __constant__ int d_P2O[112] = {
  6,5,55,1,98,71,73,77,63,96,79,15,104,4,25,23,41,43,45,17,61,65,59,57,86,21,
  35,37,39,94,110,3,69,81,84,100,102,106,47,27,75,2,67,19,49,31,33,108,51,53,
  88,90,92,29,0,
  82,
  13,12,54,8,97,70,72,76,62,95,78,14,103,11,24,22,40,42,44,16,60,64,58,56,85,
  20,34,36,38,93,109,10,68,80,83,99,101,105,46,26,74,9,66,18,48,30,32,107,50,
  52,87,89,91,28,7,
  111};

// flat LDS float pool offsets (floats)
#define OFF_A 0        // Ag 112x112=12544 -> Ap 100x104 -> assS 111x56 (6216) + HcS 56x20 (@+6216)
#define OFF_B 12544    // Xs 111x112 (P3) -> {W2s 2x1280 | Wg1s 400 @+2560} -> {TC|Tx1|Tx2|TC2} -> s2S 111x56
#define OFF_C 24976    // T64 112x64=7168 (P3: Wr1 stage) -> T20x 112x20=2240 -> Wcs 3x1120 (P16)
#define OFF_D 32144    // H1 112x64=7168 (P3: Wl1 stage) -> {H2 | H2g @ +2240}
#define FSZ   39312

__device__ __forceinline__ float lrelu(float h) { return h > 0.f ? h : 0.01f * h; }

// R11 capped unrolls (no spills) / R12 row blocking / R14 NT=1024 / R16 c-quads.
// R17: single-pass 7-row P3 & P4 (waves 0-7 LEFT, 8-15 RIGHT; Wl1 staged in H1
// slot, Wr1 in T64 slot, acc carried over a barrier before the T64 write) and
// P16b folded into P16 (softmax via lane butterflies on in-register acc; stores
// deferred past a barrier to respect the s2S/Tx alias).
__global__ __launch_bounds__(NT, 1)
void brain_fused(const float* __restrict__ features,
                 const float* __restrict__ edge_attr,
                 const int*   __restrict__ edge_index,
                 const float* __restrict__ Wl1, const float* __restrict__ bl1,
                 const float* __restrict__ Wr1, const float* __restrict__ br1,
                 const float* __restrict__ Wl2, const float* __restrict__ bl2,
                 const float* __restrict__ Wr2, const float* __restrict__ br2,
                 const float* __restrict__ Wg1, const float* __restrict__ bg1,
                 const float* __restrict__ Wrel, const float* __restrict__ brel,
                 const float* __restrict__ Wroot,
                 const float* __restrict__ Wc0, const float* __restrict__ Wc1,
                 const float* __restrict__ Wc2, const float* __restrict__ bc,
                 float* __restrict__ out)
{
    __shared__ __align__(16) float F[FSZ];
    __shared__ float disH[112], disG[112], disC[112], scoreS[112];
    __shared__ int o2rS[112], mapRank[112], permSh[KP], spSh[KP];

    float* Ag   = F + OFF_A;            // 112x112
    float* Ap   = F + OFF_A;            // 100x104
    float* assS = F + OFF_A;            // 111x56
    float* HcS  = F + OFF_A + 6216;     // 56x20
    float* Xs   = F + OFF_B;            // 111x112 permuted rows, col111=0 (P3)
    float* W2s  = F + OFF_B;            // Wl2|Wr2 (2x1280) during P5
    float* Wg1s = F + OFF_B + 2560;     // 400 floats (P7)
    float* TC   = F + OFF_B;            // 104x20
    float* Tx1  = F + OFF_B + 2080;     // 100x20
    float* Tx2  = F + OFF_B + 4080;     // 100x20
    float* TC2  = F + OFF_B + 6160;     // 104x20 (disC*Tx1, written by P14)
    float* s2S  = F + OFF_B;            // 111x56 (after P16 stores; Tx dead by then)
    float* T64  = F + OFF_C;            // 112x64 (P3: Wr1 stage, then output)
    float* T20x = F + OFF_C;            // 112x20
    float* Wcs  = F + OFF_C;            // Wc0|Wc1|Wc2 3x1120 (P16)
    float* H1   = F + OFF_D;            // 112x64
    float* Wlds = F + OFF_D;            // 112x64 Wl1 stage during P3 (row111=0)
    float* H2   = F + OFF_D;            // 112x20
    float* H2g  = F + OFF_D + 2240;     // 112x20

    const int b    = blockIdx.x;
    const int tid  = threadIdx.x;
    const int lane = tid & 63;
    const int wv   = tid >> 6;          // 0..15
    const float* x = features + (size_t)b * (N * N);

    // ---- P0: zero Ag; build orig->row map ----
    for (int o = tid; o < 12544; o += NT) Ag[o] = 0.f;
    if (tid < 112) o2rS[d_P2O[tid]] = tid;
    __syncthreads();

    // ---- P1a: scatter edges into Ag[t,s] (permuted) ----
    #pragma unroll 2
    for (int e = tid; e < NE; e += NT) {
        int s = o2rS[edge_index[e]];
        int t = o2rS[edge_index[NE + e]];
        atomicAdd(&Ag[t * NR + s], edge_attr[(size_t)b * NE + e]);
    }
    __syncthreads();

    // ---- P1b: stage x (permuted rows, stride 112, col111=0) + stage Wl1/Wr1
    //      (Wl1 -> Wlds/H1 slot, Wr1 -> T64 slot; rows 111 zeroed) ----
    #pragma unroll 2
    for (int o = tid; o < N * NR; o += NT) {
        int r = o / NR, cc = o % NR;
        Xs[o] = (cc < N) ? x[d_P2O[r] * N + cc] : 0.f;
    }
    #pragma unroll 2
    for (int o = tid; o < 1792; o += NT) {             // 112x16 float4
        float4 vl = make_float4(0.f,0.f,0.f,0.f), vr = vl;
        if (o < 1776) { vl = ((const float4*)Wl1)[o]; vr = ((const float4*)Wr1)[o]; }
        ((float4*)Wlds)[o] = vl;
        ((float4*)T64)[o]  = vr;
    }
    __syncthreads();

    // ---- P2: degrees (wave/row over 16 waves, butterfly) ----
    #pragma unroll 1
    for (int k = 0; k < 7; ++k) {
        int r = wv + 16 * k;
        if (r >= 112) continue;
        if (r == 111) { if (lane == 0) { disH[111] = 0.f; disG[111] = 0.f; } continue; }
        float a0 = Ag[r * NR + lane];
        float a1 = (lane < 48) ? Ag[r * NR + 64 + lane] : 0.f;
        float sG = a0 + a1;
        float sH;
        if (r < 55)       sH = (lane < 55) ? a0 : 0.f;
        else if (r >= 56) sH = ((lane >= 56) ? a0 : 0.f) + ((lane < 47) ? a1 : 0.f);
        else              sH = 0.f;
        #pragma unroll
        for (int m = 1; m < 64; m <<= 1) {
            sG += __shfl_xor(sG, m);
            sH += __shfl_xor(sH, m);
        }
        if (lane == 0) {
            disG[r] = 1.f / sqrtf(sG + 1.f);
            disH[r] = (r == 55) ? 0.f : 1.f / sqrtf(sH + 1.f);
        }
    }
    __syncthreads();

    // ---- P3: T64 = disH .* (x @ W1hemi) — SINGLE PASS, 7 rows/wave.
    //      waves 0-7: rows 0..55 (Wl1 in Wlds); waves 8-15: rows 56..111 (Wr1 in
    //      T64 slot). acc kept in registers across the barrier, THEN T64 written
    //      (overwriting the Wr1 stage only after all waves finished reading). ----
    {
        const bool left = (wv < 8);
        const float* W = left ? Wlds : T64;
        const int rbase = wv * 7;                       // 0..105 contiguous
        float acc[7] = {0,0,0,0,0,0,0};
        #pragma unroll 1
        for (int j4 = 0; j4 < 28; ++j4) {
            float w0 = W[(4 * j4 + 0) * 64 + lane];
            float w1 = W[(4 * j4 + 1) * 64 + lane];
            float w2 = W[(4 * j4 + 2) * 64 + lane];
            float w3 = W[(4 * j4 + 3) * 64 + lane];
            #pragma unroll
            for (int u = 0; u < 7; ++u) {
                const float4 xv = *(const float4*)&Xs[(rbase + u) * NR + 4 * j4]; // broadcast
                acc[u] += xv.x * w0 + xv.y * w1 + xv.z * w2 + xv.w * w3;
            }
        }
        __syncthreads();   // all W reads done before T64 is overwritten
        #pragma unroll
        for (int u = 0; u < 7; ++u) {
            int r = rbase + u;
            if (r < 111) T64[r * 64 + lane] = disH[r] * acc[u];   // row55: disH=0
        }
        if (wv == 15 && lane < 64) T64[111 * 64 + lane] = 0.f;    // pad row for P4
    }
    __syncthreads();

    // ---- P4 prologue: stage Wl2|Wr2 + Wg1 (Xs dead); zero H1 row 55; fence ----
    #pragma unroll 2
    for (int o = tid; o < 1280; o += NT) { W2s[o] = Wl2[o]; W2s[1280 + o] = Wr2[o]; }
    if (tid < 400) Wg1s[tid] = Wg1[tid];
    if (tid >= 448 && tid < 512) H1[55 * 64 + (tid - 448)] = 0.f;
    __syncthreads();

    // ---- P4: H1 = lrelu(disH*(Ag_block @ T64 + self) + b1) — SINGLE PASS 7-row ----
    {
        const bool left = (wv < 8);
        const int  rbase = wv * 7;
        const int  jb    = left ? 0 : 56;
        const float* bb  = left ? bl1 : br1;
        float acc[7] = {0,0,0,0,0,0,0};
        #pragma unroll 2
        for (int j4 = 0; j4 < 14; ++j4) {
            float t0 = T64[(jb + 4 * j4 + 0) * 64 + lane];
            float t1 = T64[(jb + 4 * j4 + 1) * 64 + lane];
            float t2 = T64[(jb + 4 * j4 + 2) * 64 + lane];
            float t3 = T64[(jb + 4 * j4 + 3) * 64 + lane];
            #pragma unroll
            for (int u = 0; u < 7; ++u) {
                const float4 a4 = *(const float4*)&Ag[(rbase + u) * NR + jb + 4 * j4];
                acc[u] += a4.x * t0 + a4.y * t1 + a4.z * t2 + a4.w * t3;
            }
        }
        float bv = bb[lane];
        #pragma unroll
        for (int u = 0; u < 7; ++u) {
            int r = rbase + u;
            if (r < 111 && r != 55)
                H1[r * 64 + lane] = lrelu(disH[r] * (acc[u] + T64[r * 64 + lane]) + bv);
        }
    }
    __syncthreads();

    // ---- P5: T20x quad = disH .* (H1 @ W2hemi) — c-quad (560 items) ----
    for (int o = tid; o < 560; o += NT) {
        int i = o / 5, c0 = (o % 5) * 4;
        if (i == 111) { *(float4*)&T20x[i * 20 + c0] = make_float4(0.f,0.f,0.f,0.f); continue; }
        const float* W2 = (i < 56) ? W2s : (W2s + 1280);
        const float4* h4 = (const float4*)(H1 + i * 64);
        float4 acc = make_float4(0.f,0.f,0.f,0.f);
        #pragma unroll 2
        for (int k4 = 0; k4 < 16; ++k4) {
            float4 h = h4[k4];
            float4 w0 = *(const float4*)&W2[(4 * k4 + 0) * 20 + c0];
            float4 w1 = *(const float4*)&W2[(4 * k4 + 1) * 20 + c0];
            float4 w2 = *(const float4*)&W2[(4 * k4 + 2) * 20 + c0];
            float4 w3 = *(const float4*)&W2[(4 * k4 + 3) * 20 + c0];
            acc.x += h.x * w0.x + h.y * w1.x + h.z * w2.x + h.w * w3.x;
            acc.y += h.x * w0.y + h.y * w1.y + h.z * w2.y + h.w * w3.y;
            acc.z += h.x * w0.z + h.y * w1.z + h.z * w2.z + h.w * w3.z;
            acc.w += h.x * w0.w + h.y * w1.w + h.z * w2.w + h.w * w3.w;
        }
        float d = disH[i];
        *(float4*)&T20x[i * 20 + c0] = make_float4(d*acc.x, d*acc.y, d*acc.z, d*acc.w);
    }
    __syncthreads();

    // ---- P6: H2 quad = lrelu(disH*(Ag_block @ T20x + self) + b2) — 555 items ----
    for (int o = tid; o < 555; o += NT) {
        int i = o / 5, c0 = (o % 5) * 4;
        if (i == 55) { *(float4*)&H2[i * 20 + c0] = make_float4(0.f,0.f,0.f,0.f); continue; }
        int jb = (i < 56) ? 0 : 56;
        float4 acc = make_float4(0.f,0.f,0.f,0.f);
        #pragma unroll 2
        for (int j4 = 0; j4 < 14; ++j4) {
            float4 a  = *(const float4*)&Ag[i * NR + jb + 4 * j4];
            float4 t0 = *(const float4*)&T20x[(jb + 4 * j4 + 0) * 20 + c0];
            float4 t1 = *(const float4*)&T20x[(jb + 4 * j4 + 1) * 20 + c0];
            float4 t2 = *(const float4*)&T20x[(jb + 4 * j4 + 2) * 20 + c0];
            float4 t3 = *(const float4*)&T20x[(jb + 4 * j4 + 3) * 20 + c0];
            acc.x += a.x * t0.x + a.y * t1.x + a.z * t2.x + a.w * t3.x;
            acc.y += a.x * t0.y + a.y * t1.y + a.z * t2.y + a.w * t3.y;
            acc.z += a.x * t0.z + a.y * t1.z + a.z * t2.z + a.w * t3.z;
            acc.w += a.x * t0.w + a.y * t1.w + a.z * t2.w + a.w * t3.w;
        }
        float4 self = *(const float4*)&T20x[i * 20 + c0];
        float4 bv = *(const float4*)&((i < 56) ? bl2 : br2)[c0];
        float dh = disH[i];
        float4 r;
        r.x = lrelu(dh * (acc.x + self.x) + bv.x);
        r.y = lrelu(dh * (acc.y + self.y) + bv.y);
        r.z = lrelu(dh * (acc.z + self.z) + bv.z);
        r.w = lrelu(dh * (acc.w + self.w) + bv.w);
        *(float4*)&H2[i * 20 + c0] = r;
    }
    __syncthreads();

    // ---- P7: T20x quad = disG .* (H2 @ Wg1s) — 560 items ----
    for (int o = tid; o < 560; o += NT) {
        int i = o / 5, c0 = (o % 5) * 4;
        if (i == 111) { *(float4*)&T20x[i * 20 + c0] = make_float4(0.f,0.f,0.f,0.f); continue; }
        float4 acc = make_float4(0.f,0.f,0.f,0.f);
        #pragma unroll 4
        for (int k = 0; k < 20; ++k) {
            float h = H2[i * 20 + k];
            float4 w = *(const float4*)&Wg1s[k * 20 + c0];
            acc.x += h * w.x; acc.y += h * w.y; acc.z += h * w.z; acc.w += h * w.w;
        }
        float d = disG[i];
        *(float4*)&T20x[i * 20 + c0] = make_float4(d*acc.x, d*acc.y, d*acc.z, d*acc.w);
    }
    __syncthreads();

    // ---- P8: H2g quad = lrelu(disG*(Ag @ T20x + self) + bg1) — 555 items ----
    for (int o = tid; o < 555; o += NT) {
        int i = o / 5, c0 = (o % 5) * 4;
        float4 acc = make_float4(0.f,0.f,0.f,0.f);
        #pragma unroll 2
        for (int j4 = 0; j4 < 28; ++j4) {
            float4 a  = *(const float4*)&Ag[i * NR + 4 * j4];
            float4 t0 = *(const float4*)&T20x[(4 * j4 + 0) * 20 + c0];
            float4 t1 = *(const float4*)&T20x[(4 * j4 + 1) * 20 + c0];
            float4 t2 = *(const float4*)&T20x[(4 * j4 + 2) * 20 + c0];
            float4 t3 = *(const float4*)&T20x[(4 * j4 + 3) * 20 + c0];
            acc.x += a.x * t0.x + a.y * t1.x + a.z * t2.x + a.w * t3.x;
            acc.y += a.x * t0.y + a.y * t1.y + a.z * t2.y + a.w * t3.y;
            acc.z += a.x * t0.z + a.y * t1.z + a.z * t2.z + a.w * t3.z;
            acc.w += a.x * t0.w + a.y * t1.w + a.z * t2.w + a.w * t3.w;
        }
        float4 self = *(const float4*)&T20x[i * 20 + c0];
        float4 bv = *(const float4*)&bg1[c0];
        float dg = disG[i];
        float4 r;
        r.x = lrelu(dg * (acc.x + self.x) + bv.x);
        r.y = lrelu(dg * (acc.y + self.y) + bv.y);
        r.z = lrelu(dg * (acc.z + self.z) + bv.z);
        r.w = lrelu(dg * (acc.w + self.w) + bv.w);
        *(float4*)&H2g[i * 20 + c0] = r;
    }
    __syncthreads();

    // ---- P9a: u = H2g.Wrel ; v = H2g.Wroot ----
    if (tid < 112) {
        if (tid == 111) { disC[111] = 0.f; scoreS[111] = 0.f; }
        else {
            float uu = 0.f, vv = 0.f;
            #pragma unroll 4
            for (int c = 0; c < 20; ++c) {
                float h = H2g[tid * 20 + c];
                uu += h * Wrel[c];
                vv += h * Wroot[c];
            }
            disC[tid] = uu; scoreS[tid] = vv;
        }
    }
    __syncthreads();

    // ---- P9b: score[i] = tanh(Ag row i . u + v[i] + brel) ----
    {
        float brel0 = brel[0];
        #pragma unroll 1
        for (int k = 0; k < 7; ++k) {
            int r = wv + 16 * k;
            if (r >= N) continue;
            float p = Ag[r * NR + lane] * disC[lane];
            if (lane < 48) p += Ag[r * NR + 64 + lane] * disC[64 + lane];
            #pragma unroll
            for (int m = 1; m < 64; m <<= 1) p += __shfl_xor(p, m);
            if (lane == 0) scoreS[r] = tanhf(p + scoreS[r] + brel0);
        }
    }
    __syncthreads();

    // ---- P10: rank, perm, sp ; zero Ap ----
    if (tid < N) {
        float si = scoreS[tid];
        int oi = d_P2O[tid];
        int r = 0;
        #pragma unroll 4
        for (int j = 0; j < N; ++j) {
            float sj = scoreS[j];
            r += (sj > si || (sj == si && d_P2O[j] < oi)) ? 1 : 0;
        }
        mapRank[tid] = (r < KP) ? r : -1;
        if (r < KP) permSh[r] = tid;
    }
    if (tid == N) mapRank[111] = -1;
    for (int o = tid; o < KP * APs; o += NT) Ap[o] = 0.f;
    __syncthreads();
    if (tid < N && mapRank[tid] >= 0) {
        int oi = d_P2O[tid], pos = 0;
        #pragma unroll 4
        for (int j = 0; j < N; ++j) pos += (mapRank[j] >= 0 && d_P2O[j] < oi) ? 1 : 0;
        spSh[pos] = tid;
    }
    __syncthreads();
    // ---- P11: scatter filtered adjacency (rank space) ----
    #pragma unroll 2
    for (int e = tid; e < NE; e += NT) {
        int sr = o2rS[edge_index[e]];
        int tr = o2rS[edge_index[NE + e]];
        int ms = mapRank[sr], mt = mapRank[tr];
        if (ms >= 0 && mt >= 0 && ms != mt) atomicAdd(&Ap[mt * APs + ms], 1.f);
    }
    __syncthreads();

    // ---- P12: disC from column sums of Ap ----
    if (tid < APs) {
        if (tid >= KP) disC[tid] = 0.f;
        else {
            float d0 = 0.f, d1 = 0.f;
            #pragma unroll 4
            for (int a = 0; a < KP; a += 2) {
                d0 += Ap[a * APs + tid];
                d1 += Ap[(a + 1) * APs + tid];
            }
            float d = d0 + d1;
            disC[tid] = (d > 0.f) ? 1.f / sqrtf(d) : 0.f;
        }
    }
    __syncthreads();

    // ---- P13: TC quad = disC .* h2[node]; stage Wcs; zero TC2 tail ----
    for (int o = tid; o < 520; o += NT) {
        int bq = o / 5, c0 = (o % 5) * 4;
        float4 h = *(const float4*)&H2g[o2rS[bq] * 20 + c0];
        float d = disC[bq];
        *(float4*)&TC[bq * 20 + c0] = make_float4(d*h.x, d*h.y, d*h.z, d*h.w);
    }
    #pragma unroll 2
    for (int o = tid; o < 1120; o += NT) {
        Wcs[o] = Wc0[o]; Wcs[1120 + o] = Wc1[o]; Wcs[2240 + o] = Wc2[o];
    }
    if (tid < 80) TC2[2000 + tid] = 0.f;   // rows 100..103 for P15b float4 reads
    __syncthreads();

    // ---- P14: Tx1 quad = -disC*(Ap@TC); TC2 = disC*Tx1 — 500 items ----
    for (int o = tid; o < 500; o += NT) {
        int a = o / 5, c0 = (o % 5) * 4;
        float4 acc = make_float4(0.f,0.f,0.f,0.f);
        #pragma unroll 2
        for (int j4 = 0; j4 < 26; ++j4) {
            float4 av = *(const float4*)&Ap[a * APs + 4 * j4];
            float4 t0 = *(const float4*)&TC[(4 * j4 + 0) * 20 + c0];
            float4 t1 = *(const float4*)&TC[(4 * j4 + 1) * 20 + c0];
            float4 t2 = *(const float4*)&TC[(4 * j4 + 2) * 20 + c0];
            float4 t3 = *(const float4*)&TC[(4 * j4 + 3) * 20 + c0];
            acc.x += av.x * t0.x + av.y * t1.x + av.z * t2.x + av.w * t3.x;
            acc.y += av.x * t0.y + av.y * t1.y + av.z * t2.y + av.w * t3.y;
            acc.z += av.x * t0.z + av.y * t1.z + av.z * t2.z + av.w * t3.z;
            acc.w += av.x * t0.w + av.y * t1.w + av.z * t2.w + av.w * t3.w;
        }
        float d = disC[a];
        float4 t = make_float4(-d*acc.x, -d*acc.y, -d*acc.z, -d*acc.w);
        *(float4*)&Tx1[a * 20 + c0] = t;
        *(float4*)&TC2[a * 20 + c0] = make_float4(d*t.x, d*t.y, d*t.z, d*t.w);
    }
    __syncthreads();

    // ---- P15b: Tx2 quad = -2*disC*(Ap@TC2) - h2[node] — 500 items ----
    for (int o = tid; o < 500; o += NT) {
        int a = o / 5, c0 = (o % 5) * 4;
        float4 acc = make_float4(0.f,0.f,0.f,0.f);
        #pragma unroll 2
        for (int j4 = 0; j4 < 26; ++j4) {
            float4 av = *(const float4*)&Ap[a * APs + 4 * j4];
            float4 t0 = *(const float4*)&TC2[(4 * j4 + 0) * 20 + c0];
            float4 t1 = *(const float4*)&TC2[(4 * j4 + 1) * 20 + c0];
            float4 t2 = *(const float4*)&TC2[(4 * j4 + 2) * 20 + c0];
            float4 t3 = *(const float4*)&TC2[(4 * j4 + 3) * 20 + c0];
            acc.x += av.x * t0.x + av.y * t1.x + av.z * t2.x + av.w * t3.x;
            acc.y += av.x * t0.y + av.y * t1.y + av.z * t2.y + av.w * t3.y;
            acc.z += av.x * t0.z + av.y * t1.z + av.z * t2.z + av.w * t3.z;
            acc.w += av.x * t0.w + av.y * t1.w + av.z * t2.w + av.w * t3.w;
        }
        float d2 = -2.f * disC[a];
        float4 h = *(const float4*)&H2g[o2rS[a] * 20 + c0];
        *(float4*)&Tx2[a * 20 + c0] =
            make_float4(d2*acc.x - h.x, d2*acc.y - h.y, d2*acc.z - h.z, d2*acc.w - h.w);
    }
    __syncthreads();

    // ---- P16 (+fused softmax): logits via 7-row blocking, then double softmax
    //      by lane butterflies on in-register acc; stores deferred past a
    //      barrier so the s2S region (aliases Tx1/Tx2) is safe to overwrite. ----
    {
        float bcv = (lane < CA) ? bc[lane] : 0.f;
        const int base = wv * 7;
        float acc[7] = {0,0,0,0,0,0,0};
        int ho[7], txo[7], in7[7];
        #pragma unroll
        for (int u = 0; u < 7; ++u) {
            int i = base + u;
            int ic = (i < N) ? i : (N - 1);
            ho[u]  = o2rS[ic] * 20;
            in7[u] = (ic < KP) ? 1 : 0;
            txo[u] = ((ic < KP) ? ic : 0) * 20;
        }
        #pragma unroll 1
        for (int k = 0; k < 20; ++k) {
            float w0 = Wcs[k * CA + lane];
            float w1 = Wcs[1120 + k * CA + lane];
            float w2 = Wcs[2240 + k * CA + lane];
            #pragma unroll
            for (int u = 0; u < 7; ++u) {
                float h  = H2g[ho[u] + k];
                float t1 = in7[u] ? Tx1[txo[u] + k] : 0.f;
                float t2 = in7[u] ? Tx2[txo[u] + k] : -h;
                acc[u] += h * w0 + t1 * w1 + t2 * w2;
            }
        }
        // in-register double softmax per row (lanes 0..55 = classes)
        float p1v[7], s2v[7];
        #pragma unroll 1
        for (int u = 0; u < 7; ++u) {
            float v = (lane < CA) ? acc[u] + bcv : -3.4e38f;
            float m = v;
            #pragma unroll
            for (int s = 1; s < 64; s <<= 1) m = fmaxf(m, __shfl_xor(m, s));
            float e = (lane < CA) ? expf(v - m) : 0.f;
            float sum = e;
            #pragma unroll
            for (int s = 1; s < 64; s <<= 1) sum += __shfl_xor(sum, s);
            float p1 = e / sum;
            float m2 = (lane < CA) ? p1 : -3.4e38f;
            #pragma unroll
            for (int s = 1; s < 64; s <<= 1) m2 = fmaxf(m2, __shfl_xor(m2, s));
            float e2 = (lane < CA) ? expf(p1 - m2) : 0.f;
            float sum2 = e2;
            #pragma unroll
            for (int s = 1; s < 64; s <<= 1) sum2 += __shfl_xor(sum2, s);
            p1v[u] = p1; s2v[u] = e2 / sum2;
        }
        __syncthreads();   // all Tx1/Tx2 reads complete before s2S overwrites them
        #pragma unroll
        for (int u = 0; u < 7; ++u) {
            int i = base + u;
            if (i < N && lane < CA) {
                assS[i * CA + lane] = p1v[u];
                s2S[i * CA + lane]  = s2v[u];
            }
        }
    }
    __syncthreads();

    // ---- P17: Hc quad = s2^T @ h2 — 280 items ----
    for (int o = tid; o < 280; o += NT) {
        int q = o / 5, c0 = (o % 5) * 4;
        float4 acc = make_float4(0.f,0.f,0.f,0.f);
        #pragma unroll 2
        for (int r = 0; r < N; ++r) {
            float s = s2S[d_P2O[r] * CA + q];
            float4 h = *(const float4*)&H2g[r * 20 + c0];
            acc.x += s * h.x; acc.y += s * h.y; acc.z += s * h.z; acc.w += s * h.w;
        }
        *(float4*)&HcS[q * 20 + c0] = acc;
    }
    __syncthreads();

    // ---- P18: out quad = pooled + inter @ Hc — 500 items, float4 global store ----
    for (int o = tid; o < 500; o += NT) {
        int k = o / 5, c0 = (o % 5) * 4;
        int rp = permSh[k];
        float sc = scoreS[rp];
        float4 hq = *(const float4*)&H2g[rp * 20 + c0];
        float4 v = make_float4(sc*hq.x, sc*hq.y, sc*hq.z, sc*hq.w);
        int oi = d_P2O[spSh[k]];
        if (oi < 110) {
            float4 acc = make_float4(0.f,0.f,0.f,0.f);
            #pragma unroll 4
            for (int q = 0; q < CA; ++q) {
                float s = assS[oi * CA + q];
                float4 h = *(const float4*)&HcS[q * 20 + c0];
                acc.x += s * h.x; acc.y += s * h.y; acc.z += s * h.z; acc.w += s * h.w;
            }
            v.x += acc.x; v.y += acc.y; v.z += acc.z; v.w += acc.w;
        }
        *(float4*)&out[(size_t)b * (KP * 20) + k * 20 + c0] = v;
    }
}

extern "C" void kernel_launch(void* const* d_in, const int* in_sizes, int n_in,
                              void* d_out, int out_size, void* d_ws, size_t ws_size,
                              hipStream_t stream) {
    const float* features   = (const float*)d_in[0];
    const float* edge_attr  = (const float*)d_in[1];
    // d_in[2] = adj (unused by reference)
    const int*   edge_index = (const int*)d_in[3];
    const float* Wl1 = (const float*)d_in[4];
    const float* bl1 = (const float*)d_in[5];
    const float* Wr1 = (const float*)d_in[6];
    const float* br1 = (const float*)d_in[7];
    const float* Wl2 = (const float*)d_in[8];
    const float* bl2 = (const float*)d_in[9];
    const float* Wr2 = (const float*)d_in[10];
    const float* br2 = (const float*)d_in[11];
    const float* Wg1 = (const float*)d_in[12];
    const float* bg1 = (const float*)d_in[13];
    const float* Wrel = (const float*)d_in[14];
    const float* brel = (const float*)d_in[15];
    const float* Wroot = (const float*)d_in[16];
    const float* Wc0 = (const float*)d_in[17];
    const float* Wc1 = (const float*)d_in[18];
    const float* Wc2 = (const float*)d_in[19];
    const float* bc  = (const float*)d_in[20];
    float* out = (float*)d_out;

    int B = in_sizes[0] / (N * N);
    brain_fused<<<dim3(B), dim3(NT), 0, stream>>>(
        features, edge_attr, edge_index,
        Wl1, bl1, Wr1, br1, Wl2, bl2, Wr2, br2, Wg1, bg1,
        Wrel, brel, Wroot, Wc0, Wc1, Wc2, bc, out);
}

// Round 18
// 729.887 us; speedup vs baseline: 1.2956x; 1.0433x over previous
//
#include <hip/hip_runtime.h>
#include <math.h>

#define N    111
#define NR   112      // padded row/col stride for Ag and Xs
#define NE   4000
#define KP   100
#define APs  104      // Ap col stride
#define CA   56
#define NT   1024     // 16 waves = 4/SIMD; occupancy cap for 160KB-LDS blocks (R14)

// permuted row -> original node id. rows 0..54 LEFT, 55 = node82, 56..110 RIGHT, 111 pad
__device__ __constant__ int d_P2O[112] = {
  6,5,55,1,98,71,73,77,63,96,79,15,104,4,25,23,41,43,45,17,61,65,59,57,86,21,
  35,37,39,94,110,3,69,81,84,100,102,106,47,27,75,2,67,19,49,31,33,108,51,53,
  88,90,92,29,0,
  82,
  13,12,54,8,97,70,72,76,62,95,78,14,103,11,24,22,40,42,44,16,60,64,58,56,85,
  20,34,36,38,93,109,10,68,80,83,99,101,105,46,26,74,9,66,18,48,30,32,107,50,
  52,87,89,91,28,7,
  111};

// flat LDS float pool offsets (floats)
#define OFF_A 0        // Ag 112x112=12544 -> Ap 100x104 -> assS 111x56 (6216) + HcS 56x20 (@+6216)
#define OFF_B 12544    // Xs 111x112 (P3) -> {W2s 2x1280 | Wg1s 400 @+2560} -> {TC|Tx1|Tx2|TC2} -> s2S 111x56
#define OFF_C 24976    // T64 112x64=7168 (P3: Wr1 stage) -> T20x 112x20=2240 -> Wcs 3x1120 (P16)
#define OFF_D 32144    // H1 112x64=7168 (P3: Wl1 stage) -> {H2 | H2g @ +2240}
#define FSZ   39312

__device__ __forceinline__ float lrelu(float h) { return h > 0.f ? h : 0.01f * h; }

// R11 capped unrolls / R12 row blocking / R14 NT=1024 / R16 c-quads / R17
// single-pass P3,P4 + fused softmax. R18: quad-ized operand reads in P16's
// k-loop (4 k's per iter: 12 lane w-reads + 21 broadcast float4 reads feed
// 84 FMAs; was 480 scalar LDS slots) and P18's q-loop (56 b32 -> 14 b128).
__global__ __launch_bounds__(NT, 1)
void brain_fused(const float* __restrict__ features,
                 const float* __restrict__ edge_attr,
                 const int*   __restrict__ edge_index,
                 const float* __restrict__ Wl1, const float* __restrict__ bl1,
                 const float* __restrict__ Wr1, const float* __restrict__ br1,
                 const float* __restrict__ Wl2, const float* __restrict__ bl2,
                 const float* __restrict__ Wr2, const float* __restrict__ br2,
                 const float* __restrict__ Wg1, const float* __restrict__ bg1,
                 const float* __restrict__ Wrel, const float* __restrict__ brel,
                 const float* __restrict__ Wroot,
                 const float* __restrict__ Wc0, const float* __restrict__ Wc1,
                 const float* __restrict__ Wc2, const float* __restrict__ bc,
                 float* __restrict__ out)
{
    __shared__ __align__(16) float F[FSZ];
    __shared__ float disH[112], disG[112], disC[112], scoreS[112];
    __shared__ int o2rS[112], mapRank[112], permSh[KP], spSh[KP];

    float* Ag   = F + OFF_A;            // 112x112
    float* Ap   = F + OFF_A;            // 100x104
    float* assS = F + OFF_A;            // 111x56
    float* HcS  = F + OFF_A + 6216;     // 56x20
    float* Xs   = F + OFF_B;            // 111x112 permuted rows, col111=0 (P3)
    float* W2s  = F + OFF_B;            // Wl2|Wr2 (2x1280) during P5
    float* Wg1s = F + OFF_B + 2560;     // 400 floats (P7)
    float* TC   = F + OFF_B;            // 104x20
    float* Tx1  = F + OFF_B + 2080;     // 100x20
    float* Tx2  = F + OFF_B + 4080;     // 100x20
    float* TC2  = F + OFF_B + 6160;     // 104x20 (disC*Tx1, written by P14)
    float* s2S  = F + OFF_B;            // 111x56 (after P16 stores; Tx dead by then)
    float* T64  = F + OFF_C;            // 112x64 (P3: Wr1 stage, then output)
    float* T20x = F + OFF_C;            // 112x20
    float* Wcs  = F + OFF_C;            // Wc0|Wc1|Wc2 3x1120 (P16)
    float* H1   = F + OFF_D;            // 112x64
    float* Wlds = F + OFF_D;            // 112x64 Wl1 stage during P3 (row111=0)
    float* H2   = F + OFF_D;            // 112x20
    float* H2g  = F + OFF_D + 2240;     // 112x20

    const int b    = blockIdx.x;
    const int tid  = threadIdx.x;
    const int lane = tid & 63;
    const int wv   = tid >> 6;          // 0..15
    const float* x = features + (size_t)b * (N * N);

    // ---- P0: zero Ag; build orig->row map ----
    for (int o = tid; o < 12544; o += NT) Ag[o] = 0.f;
    if (tid < 112) o2rS[d_P2O[tid]] = tid;
    __syncthreads();

    // ---- P1a: scatter edges into Ag[t,s] (permuted) ----
    #pragma unroll 2
    for (int e = tid; e < NE; e += NT) {
        int s = o2rS[edge_index[e]];
        int t = o2rS[edge_index[NE + e]];
        atomicAdd(&Ag[t * NR + s], edge_attr[(size_t)b * NE + e]);
    }
    __syncthreads();

    // ---- P1b: stage x (permuted rows, stride 112, col111=0) + stage Wl1/Wr1 ----
    #pragma unroll 2
    for (int o = tid; o < N * NR; o += NT) {
        int r = o / NR, cc = o % NR;
        Xs[o] = (cc < N) ? x[d_P2O[r] * N + cc] : 0.f;
    }
    #pragma unroll 2
    for (int o = tid; o < 1792; o += NT) {             // 112x16 float4
        float4 vl = make_float4(0.f,0.f,0.f,0.f), vr = vl;
        if (o < 1776) { vl = ((const float4*)Wl1)[o]; vr = ((const float4*)Wr1)[o]; }
        ((float4*)Wlds)[o] = vl;
        ((float4*)T64)[o]  = vr;
    }
    __syncthreads();

    // ---- P2: degrees (wave/row over 16 waves, butterfly) ----
    #pragma unroll 1
    for (int k = 0; k < 7; ++k) {
        int r = wv + 16 * k;
        if (r >= 112) continue;
        if (r == 111) { if (lane == 0) { disH[111] = 0.f; disG[111] = 0.f; } continue; }
        float a0 = Ag[r * NR + lane];
        float a1 = (lane < 48) ? Ag[r * NR + 64 + lane] : 0.f;
        float sG = a0 + a1;
        float sH;
        if (r < 55)       sH = (lane < 55) ? a0 : 0.f;
        else if (r >= 56) sH = ((lane >= 56) ? a0 : 0.f) + ((lane < 47) ? a1 : 0.f);
        else              sH = 0.f;
        #pragma unroll
        for (int m = 1; m < 64; m <<= 1) {
            sG += __shfl_xor(sG, m);
            sH += __shfl_xor(sH, m);
        }
        if (lane == 0) {
            disG[r] = 1.f / sqrtf(sG + 1.f);
            disH[r] = (r == 55) ? 0.f : 1.f / sqrtf(sH + 1.f);
        }
    }
    __syncthreads();

    // ---- P3: T64 = disH .* (x @ W1hemi) — single pass, 7 rows/wave ----
    {
        const bool left = (wv < 8);
        const float* W = left ? Wlds : T64;
        const int rbase = wv * 7;                       // 0..105 contiguous
        float acc[7] = {0,0,0,0,0,0,0};
        #pragma unroll 1
        for (int j4 = 0; j4 < 28; ++j4) {
            float w0 = W[(4 * j4 + 0) * 64 + lane];
            float w1 = W[(4 * j4 + 1) * 64 + lane];
            float w2 = W[(4 * j4 + 2) * 64 + lane];
            float w3 = W[(4 * j4 + 3) * 64 + lane];
            #pragma unroll
            for (int u = 0; u < 7; ++u) {
                const float4 xv = *(const float4*)&Xs[(rbase + u) * NR + 4 * j4]; // broadcast
                acc[u] += xv.x * w0 + xv.y * w1 + xv.z * w2 + xv.w * w3;
            }
        }
        __syncthreads();   // all W reads done before T64 is overwritten
        #pragma unroll
        for (int u = 0; u < 7; ++u) {
            int r = rbase + u;
            if (r < 111) T64[r * 64 + lane] = disH[r] * acc[u];   // row55: disH=0
        }
        if (wv == 15 && lane < 64) T64[111 * 64 + lane] = 0.f;    // pad row for P4
    }
    __syncthreads();

    // ---- P4 prologue: stage Wl2|Wr2 + Wg1 (Xs dead); zero H1 row 55; fence ----
    #pragma unroll 2
    for (int o = tid; o < 1280; o += NT) { W2s[o] = Wl2[o]; W2s[1280 + o] = Wr2[o]; }
    if (tid < 400) Wg1s[tid] = Wg1[tid];
    if (tid >= 448 && tid < 512) H1[55 * 64 + (tid - 448)] = 0.f;
    __syncthreads();

    // ---- P4: H1 = lrelu(disH*(Ag_block @ T64 + self) + b1) — single pass 7-row ----
    {
        const bool left = (wv < 8);
        const int  rbase = wv * 7;
        const int  jb    = left ? 0 : 56;
        const float* bb  = left ? bl1 : br1;
        float acc[7] = {0,0,0,0,0,0,0};
        #pragma unroll 2
        for (int j4 = 0; j4 < 14; ++j4) {
            float t0 = T64[(jb + 4 * j4 + 0) * 64 + lane];
            float t1 = T64[(jb + 4 * j4 + 1) * 64 + lane];
            float t2 = T64[(jb + 4 * j4 + 2) * 64 + lane];
            float t3 = T64[(jb + 4 * j4 + 3) * 64 + lane];
            #pragma unroll
            for (int u = 0; u < 7; ++u) {
                const float4 a4 = *(const float4*)&Ag[(rbase + u) * NR + jb + 4 * j4];
                acc[u] += a4.x * t0 + a4.y * t1 + a4.z * t2 + a4.w * t3;
            }
        }
        float bv = bb[lane];
        #pragma unroll
        for (int u = 0; u < 7; ++u) {
            int r = rbase + u;
            if (r < 111 && r != 55)
                H1[r * 64 + lane] = lrelu(disH[r] * (acc[u] + T64[r * 64 + lane]) + bv);
        }
    }
    __syncthreads();

    // ---- P5: T20x quad = disH .* (H1 @ W2hemi) — c-quad (560 items) ----
    for (int o = tid; o < 560; o += NT) {
        int i = o / 5, c0 = (o % 5) * 4;
        if (i == 111) { *(float4*)&T20x[i * 20 + c0] = make_float4(0.f,0.f,0.f,0.f); continue; }
        const float* W2 = (i < 56) ? W2s : (W2s + 1280);
        const float4* h4 = (const float4*)(H1 + i * 64);
        float4 acc = make_float4(0.f,0.f,0.f,0.f);
        #pragma unroll 2
        for (int k4 = 0; k4 < 16; ++k4) {
            float4 h = h4[k4];
            float4 w0 = *(const float4*)&W2[(4 * k4 + 0) * 20 + c0];
            float4 w1 = *(const float4*)&W2[(4 * k4 + 1) * 20 + c0];
            float4 w2 = *(const float4*)&W2[(4 * k4 + 2) * 20 + c0];
            float4 w3 = *(const float4*)&W2[(4 * k4 + 3) * 20 + c0];
            acc.x += h.x * w0.x + h.y * w1.x + h.z * w2.x + h.w * w3.x;
            acc.y += h.x * w0.y + h.y * w1.y + h.z * w2.y + h.w * w3.y;
            acc.z += h.x * w0.z + h.y * w1.z + h.z * w2.z + h.w * w3.z;
            acc.w += h.x * w0.w + h.y * w1.w + h.z * w2.w + h.w * w3.w;
        }
        float d = disH[i];
        *(float4*)&T20x[i * 20 + c0] = make_float4(d*acc.x, d*acc.y, d*acc.z, d*acc.w);
    }
    __syncthreads();

    // ---- P6: H2 quad = lrelu(disH*(Ag_block @ T20x + self) + b2) — 555 items ----
    for (int o = tid; o < 555; o += NT) {
        int i = o / 5, c0 = (o % 5) * 4;
        if (i == 55) { *(float4*)&H2[i * 20 + c0] = make_float4(0.f,0.f,0.f,0.f); continue; }
        int jb = (i < 56) ? 0 : 56;
        float4 acc = make_float4(0.f,0.f,0.f,0.f);
        #pragma unroll 2
        for (int j4 = 0; j4 < 14; ++j4) {
            float4 a  = *(const float4*)&Ag[i * NR + jb + 4 * j4];
            float4 t0 = *(const float4*)&T20x[(jb + 4 * j4 + 0) * 20 + c0];
            float4 t1 = *(const float4*)&T20x[(jb + 4 * j4 + 1) * 20 + c0];
            float4 t2 = *(const float4*)&T20x[(jb + 4 * j4 + 2) * 20 + c0];
            float4 t3 = *(const float4*)&T20x[(jb + 4 * j4 + 3) * 20 + c0];
            acc.x += a.x * t0.x + a.y * t1.x + a.z * t2.x + a.w * t3.x;
            acc.y += a.x * t0.y + a.y * t1.y + a.z * t2.y + a.w * t3.y;
            acc.z += a.x * t0.z + a.y * t1.z + a.z * t2.z + a.w * t3.z;
            acc.w += a.x * t0.w + a.y * t1.w + a.z * t2.w + a.w * t3.w;
        }
        float4 self = *(const float4*)&T20x[i * 20 + c0];
        float4 bv = *(const float4*)&((i < 56) ? bl2 : br2)[c0];
        float dh = disH[i];
        float4 r;
        r.x = lrelu(dh * (acc.x + self.x) + bv.x);
        r.y = lrelu(dh * (acc.y + self.y) + bv.y);
        r.z = lrelu(dh * (acc.z + self.z) + bv.z);
        r.w = lrelu(dh * (acc.w + self.w) + bv.w);
        *(float4*)&H2[i * 20 + c0] = r;
    }
    __syncthreads();

    // ---- P7: T20x quad = disG .* (H2 @ Wg1s) — 560 items ----
    for (int o = tid; o < 560; o += NT) {
        int i = o / 5, c0 = (o % 5) * 4;
        if (i == 111) { *(float4*)&T20x[i * 20 + c0] = make_float4(0.f,0.f,0.f,0.f); continue; }
        float4 acc = make_float4(0.f,0.f,0.f,0.f);
        #pragma unroll 4
        for (int k = 0; k < 20; ++k) {
            float h = H2[i * 20 + k];
            float4 w = *(const float4*)&Wg1s[k * 20 + c0];
            acc.x += h * w.x; acc.y += h * w.y; acc.z += h * w.z; acc.w += h * w.w;
        }
        float d = disG[i];
        *(float4*)&T20x[i * 20 + c0] = make_float4(d*acc.x, d*acc.y, d*acc.z, d*acc.w);
    }
    __syncthreads();

    // ---- P8: H2g quad = lrelu(disG*(Ag @ T20x + self) + bg1) — 555 items ----
    for (int o = tid; o < 555; o += NT) {
        int i = o / 5, c0 = (o % 5) * 4;
        float4 acc = make_float4(0.f,0.f,0.f,0.f);
        #pragma unroll 2
        for (int j4 = 0; j4 < 28; ++j4) {
            float4 a  = *(const float4*)&Ag[i * NR + 4 * j4];
            float4 t0 = *(const float4*)&T20x[(4 * j4 + 0) * 20 + c0];
            float4 t1 = *(const float4*)&T20x[(4 * j4 + 1) * 20 + c0];
            float4 t2 = *(const float4*)&T20x[(4 * j4 + 2) * 20 + c0];
            float4 t3 = *(const float4*)&T20x[(4 * j4 + 3) * 20 + c0];
            acc.x += a.x * t0.x + a.y * t1.x + a.z * t2.x + a.w * t3.x;
            acc.y += a.x * t0.y + a.y * t1.y + a.z * t2.y + a.w * t3.y;
            acc.z += a.x * t0.z + a.y * t1.z + a.z * t2.z + a.w * t3.z;
            acc.w += a.x * t0.w + a.y * t1.w + a.z * t2.w + a.w * t3.w;
        }
        float4 self = *(const float4*)&T20x[i * 20 + c0];
        float4 bv = *(const float4*)&bg1[c0];
        float dg = disG[i];
        float4 r;
        r.x = lrelu(dg * (acc.x + self.x) + bv.x);
        r.y = lrelu(dg * (acc.y + self.y) + bv.y);
        r.z = lrelu(dg * (acc.z + self.z) + bv.z);
        r.w = lrelu(dg * (acc.w + self.w) + bv.w);
        *(float4*)&H2g[i * 20 + c0] = r;
    }
    __syncthreads();

    // ---- P9a: u = H2g.Wrel ; v = H2g.Wroot ----
    if (tid < 112) {
        if (tid == 111) { disC[111] = 0.f; scoreS[111] = 0.f; }
        else {
            float uu = 0.f, vv = 0.f;
            #pragma unroll 4
            for (int c = 0; c < 20; ++c) {
                float h = H2g[tid * 20 + c];
                uu += h * Wrel[c];
                vv += h * Wroot[c];
            }
            disC[tid] = uu; scoreS[tid] = vv;
        }
    }
    __syncthreads();

    // ---- P9b: score[i] = tanh(Ag row i . u + v[i] + brel) ----
    {
        float brel0 = brel[0];
        #pragma unroll 1
        for (int k = 0; k < 7; ++k) {
            int r = wv + 16 * k;
            if (r >= N) continue;
            float p = Ag[r * NR + lane] * disC[lane];
            if (lane < 48) p += Ag[r * NR + 64 + lane] * disC[64 + lane];
            #pragma unroll
            for (int m = 1; m < 64; m <<= 1) p += __shfl_xor(p, m);
            if (lane == 0) scoreS[r] = tanhf(p + scoreS[r] + brel0);
        }
    }
    __syncthreads();

    // ---- P10: rank, perm, sp ; zero Ap ----
    if (tid < N) {
        float si = scoreS[tid];
        int oi = d_P2O[tid];
        int r = 0;
        #pragma unroll 4
        for (int j = 0; j < N; ++j) {
            float sj = scoreS[j];
            r += (sj > si || (sj == si && d_P2O[j] < oi)) ? 1 : 0;
        }
        mapRank[tid] = (r < KP) ? r : -1;
        if (r < KP) permSh[r] = tid;
    }
    if (tid == N) mapRank[111] = -1;
    for (int o = tid; o < KP * APs; o += NT) Ap[o] = 0.f;
    __syncthreads();
    if (tid < N && mapRank[tid] >= 0) {
        int oi = d_P2O[tid], pos = 0;
        #pragma unroll 4
        for (int j = 0; j < N; ++j) pos += (mapRank[j] >= 0 && d_P2O[j] < oi) ? 1 : 0;
        spSh[pos] = tid;
    }
    __syncthreads();
    // ---- P11: scatter filtered adjacency (rank space) ----
    #pragma unroll 2
    for (int e = tid; e < NE; e += NT) {
        int sr = o2rS[edge_index[e]];
        int tr = o2rS[edge_index[NE + e]];
        int ms = mapRank[sr], mt = mapRank[tr];
        if (ms >= 0 && mt >= 0 && ms != mt) atomicAdd(&Ap[mt * APs + ms], 1.f);
    }
    __syncthreads();

    // ---- P12: disC from column sums of Ap ----
    if (tid < APs) {
        if (tid >= KP) disC[tid] = 0.f;
        else {
            float d0 = 0.f, d1 = 0.f;
            #pragma unroll 4
            for (int a = 0; a < KP; a += 2) {
                d0 += Ap[a * APs + tid];
                d1 += Ap[(a + 1) * APs + tid];
            }
            float d = d0 + d1;
            disC[tid] = (d > 0.f) ? 1.f / sqrtf(d) : 0.f;
        }
    }
    __syncthreads();

    // ---- P13: TC quad = disC .* h2[node]; stage Wcs; zero TC2 tail ----
    for (int o = tid; o < 520; o += NT) {
        int bq = o / 5, c0 = (o % 5) * 4;
        float4 h = *(const float4*)&H2g[o2rS[bq] * 20 + c0];
        float d = disC[bq];
        *(float4*)&TC[bq * 20 + c0] = make_float4(d*h.x, d*h.y, d*h.z, d*h.w);
    }
    #pragma unroll 2
    for (int o = tid; o < 1120; o += NT) {
        Wcs[o] = Wc0[o]; Wcs[1120 + o] = Wc1[o]; Wcs[2240 + o] = Wc2[o];
    }
    if (tid < 80) TC2[2000 + tid] = 0.f;   // rows 100..103 for P15b float4 reads
    __syncthreads();

    // ---- P14: Tx1 quad = -disC*(Ap@TC); TC2 = disC*Tx1 — 500 items ----
    for (int o = tid; o < 500; o += NT) {
        int a = o / 5, c0 = (o % 5) * 4;
        float4 acc = make_float4(0.f,0.f,0.f,0.f);
        #pragma unroll 2
        for (int j4 = 0; j4 < 26; ++j4) {
            float4 av = *(const float4*)&Ap[a * APs + 4 * j4];
            float4 t0 = *(const float4*)&TC[(4 * j4 + 0) * 20 + c0];
            float4 t1 = *(const float4*)&TC[(4 * j4 + 1) * 20 + c0];
            float4 t2 = *(const float4*)&TC[(4 * j4 + 2) * 20 + c0];
            float4 t3 = *(const float4*)&TC[(4 * j4 + 3) * 20 + c0];
            acc.x += av.x * t0.x + av.y * t1.x + av.z * t2.x + av.w * t3.x;
            acc.y += av.x * t0.y + av.y * t1.y + av.z * t2.y + av.w * t3.y;
            acc.z += av.x * t0.z + av.y * t1.z + av.z * t2.z + av.w * t3.z;
            acc.w += av.x * t0.w + av.y * t1.w + av.z * t2.w + av.w * t3.w;
        }
        float d = disC[a];
        float4 t = make_float4(-d*acc.x, -d*acc.y, -d*acc.z, -d*acc.w);
        *(float4*)&Tx1[a * 20 + c0] = t;
        *(float4*)&TC2[a * 20 + c0] = make_float4(d*t.x, d*t.y, d*t.z, d*t.w);
    }
    __syncthreads();

    // ---- P15b: Tx2 quad = -2*disC*(Ap@TC2) - h2[node] — 500 items ----
    for (int o = tid; o < 500; o += NT) {
        int a = o / 5, c0 = (o % 5) * 4;
        float4 acc = make_float4(0.f,0.f,0.f,0.f);
        #pragma unroll 2
        for (int j4 = 0; j4 < 26; ++j4) {
            float4 av = *(const float4*)&Ap[a * APs + 4 * j4];
            float4 t0 = *(const float4*)&TC2[(4 * j4 + 0) * 20 + c0];
            float4 t1 = *(const float4*)&TC2[(4 * j4 + 1) * 20 + c0];
            float4 t2 = *(const float4*)&TC2[(4 * j4 + 2) * 20 + c0];
            float4 t3 = *(const float4*)&TC2[(4 * j4 + 3) * 20 + c0];
            acc.x += av.x * t0.x + av.y * t1.x + av.z * t2.x + av.w * t3.x;
            acc.y += av.x * t0.y + av.y * t1.y + av.z * t2.y + av.w * t3.y;
            acc.z += av.x * t0.z + av.y * t1.z + av.z * t2.z + av.w * t3.z;
            acc.w += av.x * t0.w + av.y * t1.w + av.z * t2.w + av.w * t3.w;
        }
        float d2 = -2.f * disC[a];
        float4 h = *(const float4*)&H2g[o2rS[a] * 20 + c0];
        *(float4*)&Tx2[a * 20 + c0] =
            make_float4(d2*acc.x - h.x, d2*acc.y - h.y, d2*acc.z - h.z, d2*acc.w - h.w);
    }
    __syncthreads();

    // ---- P16 (+fused softmax): logits, k4-QUAD operand reads (R18), then
    //      double softmax via lane butterflies; stores after barrier. ----
    {
        float bcv = (lane < CA) ? bc[lane] : 0.f;
        const int base = wv * 7;
        float acc[7] = {0,0,0,0,0,0,0};
        int ho[7], txo[7], in7[7];
        #pragma unroll
        for (int u = 0; u < 7; ++u) {
            int i = base + u;
            int ic = (i < N) ? i : (N - 1);
            ho[u]  = o2rS[ic] * 20;
            in7[u] = (ic < KP) ? 1 : 0;
            txo[u] = ((ic < KP) ? ic : 0) * 20;
        }
        #pragma unroll 1
        for (int k4 = 0; k4 < 5; ++k4) {
            float w0[4], w1[4], w2[4];
            #pragma unroll
            for (int q = 0; q < 4; ++q) {
                int k = 4 * k4 + q;
                w0[q] = Wcs[k * CA + lane];
                w1[q] = Wcs[1120 + k * CA + lane];
                w2[q] = Wcs[2240 + k * CA + lane];
            }
            #pragma unroll
            for (int u = 0; u < 7; ++u) {
                float4 h = *(const float4*)&H2g[ho[u] + 4 * k4];      // broadcast
                float4 t1, t2;
                if (in7[u]) {
                    t1 = *(const float4*)&Tx1[txo[u] + 4 * k4];
                    t2 = *(const float4*)&Tx2[txo[u] + 4 * k4];
                } else {
                    t1 = make_float4(0.f,0.f,0.f,0.f);
                    t2 = make_float4(-h.x,-h.y,-h.z,-h.w);
                }
                acc[u] += h.x*w0[0] + h.y*w0[1] + h.z*w0[2] + h.w*w0[3]
                        + t1.x*w1[0] + t1.y*w1[1] + t1.z*w1[2] + t1.w*w1[3]
                        + t2.x*w2[0] + t2.y*w2[1] + t2.z*w2[2] + t2.w*w2[3];
            }
        }
        // in-register double softmax per row (lanes 0..55 = classes)
        float p1v[7], s2v[7];
        #pragma unroll 1
        for (int u = 0; u < 7; ++u) {
            float v = (lane < CA) ? acc[u] + bcv : -3.4e38f;
            float m = v;
            #pragma unroll
            for (int s = 1; s < 64; s <<= 1) m = fmaxf(m, __shfl_xor(m, s));
            float e = (lane < CA) ? expf(v - m) : 0.f;
            float sum = e;
            #pragma unroll
            for (int s = 1; s < 64; s <<= 1) sum += __shfl_xor(sum, s);
            float p1 = e / sum;
            float m2 = (lane < CA) ? p1 : -3.4e38f;
            #pragma unroll
            for (int s = 1; s < 64; s <<= 1) m2 = fmaxf(m2, __shfl_xor(m2, s));
            float e2 = (lane < CA) ? expf(p1 - m2) : 0.f;
            float sum2 = e2;
            #pragma unroll
            for (int s = 1; s < 64; s <<= 1) sum2 += __shfl_xor(sum2, s);
            p1v[u] = p1; s2v[u] = e2 / sum2;
        }
        __syncthreads();   // all Tx1/Tx2 reads complete before s2S overwrites them
        #pragma unroll
        for (int u = 0; u < 7; ++u) {
            int i = base + u;
            if (i < N && lane < CA) {
                assS[i * CA + lane] = p1v[u];
                s2S[i * CA + lane]  = s2v[u];
            }
        }
    }
    __syncthreads();

    // ---- P17: Hc quad = s2^T @ h2 — 280 items ----
    for (int o = tid; o < 280; o += NT) {
        int q = o / 5, c0 = (o % 5) * 4;
        float4 acc = make_float4(0.f,0.f,0.f,0.f);
        #pragma unroll 2
        for (int r = 0; r < N; ++r) {
            float s = s2S[d_P2O[r] * CA + q];
            float4 h = *(const float4*)&H2g[r * 20 + c0];
            acc.x += s * h.x; acc.y += s * h.y; acc.z += s * h.z; acc.w += s * h.w;
        }
        *(float4*)&HcS[q * 20 + c0] = acc;
    }
    __syncthreads();

    // ---- P18: out quad = pooled + inter @ Hc — q4-QUAD assS reads (R18) ----
    for (int o = tid; o < 500; o += NT) {
        int k = o / 5, c0 = (o % 5) * 4;
        int rp = permSh[k];
        float sc = scoreS[rp];
        float4 hq = *(const float4*)&H2g[rp * 20 + c0];
        float4 v = make_float4(sc*hq.x, sc*hq.y, sc*hq.z, sc*hq.w);
        int oi = d_P2O[spSh[k]];
        if (oi < 110) {
            float4 acc = make_float4(0.f,0.f,0.f,0.f);
            #pragma unroll 2
            for (int q4 = 0; q4 < 14; ++q4) {
                float4 s  = *(const float4*)&assS[oi * CA + 4 * q4];  // broadcast
                float4 h0 = *(const float4*)&HcS[(4 * q4 + 0) * 20 + c0];
                float4 h1 = *(const float4*)&HcS[(4 * q4 + 1) * 20 + c0];
                float4 h2 = *(const float4*)&HcS[(4 * q4 + 2) * 20 + c0];
                float4 h3 = *(const float4*)&HcS[(4 * q4 + 3) * 20 + c0];
                acc.x += s.x * h0.x + s.y * h1.x + s.z * h2.x + s.w * h3.x;
                acc.y += s.x * h0.y + s.y * h1.y + s.z * h2.y + s.w * h3.y;
                acc.z += s.x * h0.z + s.y * h1.z + s.z * h2.z + s.w * h3.z;
                acc.w += s.x * h0.w + s.y * h1.w + s.z * h2.w + s.w * h3.w;
            }
            v.x += acc.x; v.y += acc.y; v.z += acc.z; v.w += acc.w;
        }
        *(float4*)&out[(size_t)b * (KP * 20) + k * 20 + c0] = v;
    }
}

extern "C" void kernel_launch(void* const* d_in, const int* in_sizes, int n_in,
                              void* d_out, int out_size, void* d_ws, size_t ws_size,
                              hipStream_t stream) {
    const float* features   = (const float*)d_in[0];
    const float* edge_attr  = (const float*)d_in[1];
    // d_in[2] = adj (unused by reference)
    const int*   edge_index = (const int*)d_in[3];
    const float* Wl1 = (const float*)d_in[4];
    const float* bl1 = (const float*)d_in[5];
    const float* Wr1 = (const float*)d_in[6];
    const float* br1 = (const float*)d_in[7];
    const float* Wl2 = (const float*)d_in[8];
    const float* bl2 = (const float*)d_in[9];
    const float* Wr2 = (const float*)d_in[10];
    const float* br2 = (const float*)d_in[11];
    const float* Wg1 = (const float*)d_in[12];
    const float* bg1 = (const float*)d_in[13];
    const float* Wrel = (const float*)d_in[14];
    const float* brel = (const float*)d_in[15];
    const float* Wroot = (const float*)d_in[16];
    const float* Wc0 = (const float*)d_in[17];
    const float* Wc1 = (const float*)d_in[18];
    const float* Wc2 = (const float*)d_in[19];
    const float* bc  = (const float*)d_in[20];
    float* out = (float*)d_out;

    int B = in_sizes[0] / (N * N);
    brain_fused<<<dim3(B), dim3(NT), 0, stream>>>(
        features, edge_attr, edge_index,
        Wl1, bl1, Wr1, br1, Wl2, bl2, Wr2, br2, Wg1, bg1,
        Wrel, brel, Wroot, Wc0, Wc1, Wc2, bc, out);
}

// Round 19
// 723.285 us; speedup vs baseline: 1.3074x; 1.0091x over previous
//
#include <hip/hip_runtime.h>
#include <math.h>

#define N    111
#define NR   112      // padded row/col stride for Ag and Xs
#define NE   4000
#define KP   100
#define APs  104      // Ap col stride
#define CA   56
#define NT   1024     // 16 waves = 4/SIMD; occupancy cap for 160KB-LDS blocks (R14)

// permuted row -> original node id. rows 0..54 LEFT, 55 = node82, 56..110 RIGHT, 111 pad
__device__ __constant__ int d_P2O[112] = {
  6,5,55,1,98,71,73,77,63,96,79,15,104,4,25,23,41,43,45,17,61,65,59,57,86,21,
  35,37,39,94,110,3,69,81,84,100,102,106,47,27,75,2,67,19,49,31,33,108,51,53,
  88,90,92,29,0,
  82,
  13,12,54,8,97,70,72,76,62,95,78,14,103,11,24,22,40,42,44,16,60,64,58,56,85,
  20,34,36,38,93,109,10,68,80,83,99,101,105,46,26,74,9,66,18,48,30,32,107,50,
  52,87,89,91,28,7,
  111};

// flat LDS float pool offsets (floats)
#define OFF_A 0        // Ag 112x112=12544 -> Ap 100x104 -> {assS 111x56 | s2S 111x56 @+6216} (12432<=12544)
#define OFF_B 12544    // Xs 111x112 (P3) -> {W2s 2x1280 | Wg1s 400 @+2560} -> {TC|Tx1|Tx2|TC2}
#define OFF_C 24976    // T64 112x64=7168 (P3: Wr1 stage) -> T20x 112x20=2240 -> Wcs 3x1120 (P16)
#define OFF_D 32144    // H1 112x64=7168 (P3: Wl1 stage) -> {H2 | H2g @+2240 | HcS @+4480}
#define FSZ   39312

__device__ __forceinline__ float lrelu(float h) { return h > 0.f ? h : 0.01f * h; }

// R11 capped unrolls / R12 row blocking / R14 NT=1024 / R16 c-quads / R17
// single-pass P3,P4 + fused softmax / R18 quad P16/P18 reads.
// R19: s2S relocated to OFF_A+6216 (Ap dead region; no longer aliases Tx1/Tx2)
// and HcS to OFF_D+4480 -> P16 stores softmax results immediately per row:
// deletes p1v/s2v deferred-store arrays (-14 live VGPRs, kills the R18 spill)
// and one intra-phase barrier.
__global__ __launch_bounds__(NT, 1)
void brain_fused(const float* __restrict__ features,
                 const float* __restrict__ edge_attr,
                 const int*   __restrict__ edge_index,
                 const float* __restrict__ Wl1, const float* __restrict__ bl1,
                 const float* __restrict__ Wr1, const float* __restrict__ br1,
                 const float* __restrict__ Wl2, const float* __restrict__ bl2,
                 const float* __restrict__ Wr2, const float* __restrict__ br2,
                 const float* __restrict__ Wg1, const float* __restrict__ bg1,
                 const float* __restrict__ Wrel, const float* __restrict__ brel,
                 const float* __restrict__ Wroot,
                 const float* __restrict__ Wc0, const float* __restrict__ Wc1,
                 const float* __restrict__ Wc2, const float* __restrict__ bc,
                 float* __restrict__ out)
{
    __shared__ __align__(16) float F[FSZ];
    __shared__ float disH[112], disG[112], disC[112], scoreS[112];
    __shared__ int o2rS[112], mapRank[112], permSh[KP], spSh[KP];

    float* Ag   = F + OFF_A;            // 112x112
    float* Ap   = F + OFF_A;            // 100x104
    float* assS = F + OFF_A;            // 111x56
    float* s2S  = F + OFF_A + 6216;     // 111x56 (R19: over dead Ap tail)
    float* Xs   = F + OFF_B;            // 111x112 permuted rows, col111=0 (P3)
    float* W2s  = F + OFF_B;            // Wl2|Wr2 (2x1280) during P5
    float* Wg1s = F + OFF_B + 2560;     // 400 floats (P7)
    float* TC   = F + OFF_B;            // 104x20
    float* Tx1  = F + OFF_B + 2080;     // 100x20
    float* Tx2  = F + OFF_B + 4080;     // 100x20
    float* TC2  = F + OFF_B + 6160;     // 104x20 (disC*Tx1, written by P14)
    float* T64  = F + OFF_C;            // 112x64 (P3: Wr1 stage, then output)
    float* T20x = F + OFF_C;            // 112x20
    float* Wcs  = F + OFF_C;            // Wc0|Wc1|Wc2 3x1120 (P16)
    float* H1   = F + OFF_D;            // 112x64
    float* Wlds = F + OFF_D;            // 112x64 Wl1 stage during P3 (row111=0)
    float* H2   = F + OFF_D;            // 112x20
    float* H2g  = F + OFF_D + 2240;     // 112x20
    float* HcS  = F + OFF_D + 4480;     // 56x20 (R19: H1 dead region)

    const int b    = blockIdx.x;
    const int tid  = threadIdx.x;
    const int lane = tid & 63;
    const int wv   = tid >> 6;          // 0..15
    const float* x = features + (size_t)b * (N * N);

    // ---- P0: zero Ag; build orig->row map ----
    for (int o = tid; o < 12544; o += NT) Ag[o] = 0.f;
    if (tid < 112) o2rS[d_P2O[tid]] = tid;
    __syncthreads();

    // ---- P1a: scatter edges into Ag[t,s] (permuted) ----
    #pragma unroll 2
    for (int e = tid; e < NE; e += NT) {
        int s = o2rS[edge_index[e]];
        int t = o2rS[edge_index[NE + e]];
        atomicAdd(&Ag[t * NR + s], edge_attr[(size_t)b * NE + e]);
    }
    __syncthreads();

    // ---- P1b: stage x (permuted rows, stride 112, col111=0) + stage Wl1/Wr1 ----
    #pragma unroll 2
    for (int o = tid; o < N * NR; o += NT) {
        int r = o / NR, cc = o % NR;
        Xs[o] = (cc < N) ? x[d_P2O[r] * N + cc] : 0.f;
    }
    #pragma unroll 2
    for (int o = tid; o < 1792; o += NT) {             // 112x16 float4
        float4 vl = make_float4(0.f,0.f,0.f,0.f), vr = vl;
        if (o < 1776) { vl = ((const float4*)Wl1)[o]; vr = ((const float4*)Wr1)[o]; }
        ((float4*)Wlds)[o] = vl;
        ((float4*)T64)[o]  = vr;
    }
    __syncthreads();

    // ---- P2: degrees (wave/row over 16 waves, butterfly) ----
    #pragma unroll 1
    for (int k = 0; k < 7; ++k) {
        int r = wv + 16 * k;
        if (r >= 112) continue;
        if (r == 111) { if (lane == 0) { disH[111] = 0.f; disG[111] = 0.f; } continue; }
        float a0 = Ag[r * NR + lane];
        float a1 = (lane < 48) ? Ag[r * NR + 64 + lane] : 0.f;
        float sG = a0 + a1;
        float sH;
        if (r < 55)       sH = (lane < 55) ? a0 : 0.f;
        else if (r >= 56) sH = ((lane >= 56) ? a0 : 0.f) + ((lane < 47) ? a1 : 0.f);
        else              sH = 0.f;
        #pragma unroll
        for (int m = 1; m < 64; m <<= 1) {
            sG += __shfl_xor(sG, m);
            sH += __shfl_xor(sH, m);
        }
        if (lane == 0) {
            disG[r] = 1.f / sqrtf(sG + 1.f);
            disH[r] = (r == 55) ? 0.f : 1.f / sqrtf(sH + 1.f);
        }
    }
    __syncthreads();

    // ---- P3: T64 = disH .* (x @ W1hemi) — single pass, 7 rows/wave ----
    {
        const bool left = (wv < 8);
        const float* W = left ? Wlds : T64;
        const int rbase = wv * 7;                       // 0..105 contiguous
        float acc[7] = {0,0,0,0,0,0,0};
        #pragma unroll 1
        for (int j4 = 0; j4 < 28; ++j4) {
            float w0 = W[(4 * j4 + 0) * 64 + lane];
            float w1 = W[(4 * j4 + 1) * 64 + lane];
            float w2 = W[(4 * j4 + 2) * 64 + lane];
            float w3 = W[(4 * j4 + 3) * 64 + lane];
            #pragma unroll
            for (int u = 0; u < 7; ++u) {
                const float4 xv = *(const float4*)&Xs[(rbase + u) * NR + 4 * j4]; // broadcast
                acc[u] += xv.x * w0 + xv.y * w1 + xv.z * w2 + xv.w * w3;
            }
        }
        __syncthreads();   // all W reads done before T64 is overwritten
        #pragma unroll
        for (int u = 0; u < 7; ++u) {
            int r = rbase + u;
            if (r < 111) T64[r * 64 + lane] = disH[r] * acc[u];   // row55: disH=0
        }
        if (wv == 15 && lane < 64) T64[111 * 64 + lane] = 0.f;    // pad row for P4
    }
    __syncthreads();

    // ---- P4 prologue: stage Wl2|Wr2 + Wg1 (Xs dead); zero H1 row 55; fence ----
    #pragma unroll 2
    for (int o = tid; o < 1280; o += NT) { W2s[o] = Wl2[o]; W2s[1280 + o] = Wr2[o]; }
    if (tid < 400) Wg1s[tid] = Wg1[tid];
    if (tid >= 448 && tid < 512) H1[55 * 64 + (tid - 448)] = 0.f;
    __syncthreads();

    // ---- P4: H1 = lrelu(disH*(Ag_block @ T64 + self) + b1) — single pass 7-row ----
    {
        const bool left = (wv < 8);
        const int  rbase = wv * 7;
        const int  jb    = left ? 0 : 56;
        const float* bb  = left ? bl1 : br1;
        float acc[7] = {0,0,0,0,0,0,0};
        #pragma unroll 2
        for (int j4 = 0; j4 < 14; ++j4) {
            float t0 = T64[(jb + 4 * j4 + 0) * 64 + lane];
            float t1 = T64[(jb + 4 * j4 + 1) * 64 + lane];
            float t2 = T64[(jb + 4 * j4 + 2) * 64 + lane];
            float t3 = T64[(jb + 4 * j4 + 3) * 64 + lane];
            #pragma unroll
            for (int u = 0; u < 7; ++u) {
                const float4 a4 = *(const float4*)&Ag[(rbase + u) * NR + jb + 4 * j4];
                acc[u] += a4.x * t0 + a4.y * t1 + a4.z * t2 + a4.w * t3;
            }
        }
        float bv = bb[lane];
        #pragma unroll
        for (int u = 0; u < 7; ++u) {
            int r = rbase + u;
            if (r < 111 && r != 55)
                H1[r * 64 + lane] = lrelu(disH[r] * (acc[u] + T64[r * 64 + lane]) + bv);
        }
    }
    __syncthreads();

    // ---- P5: T20x quad = disH .* (H1 @ W2hemi) — c-quad (560 items) ----
    for (int o = tid; o < 560; o += NT) {
        int i = o / 5, c0 = (o % 5) * 4;
        if (i == 111) { *(float4*)&T20x[i * 20 + c0] = make_float4(0.f,0.f,0.f,0.f); continue; }
        const float* W2 = (i < 56) ? W2s : (W2s + 1280);
        const float4* h4 = (const float4*)(H1 + i * 64);
        float4 acc = make_float4(0.f,0.f,0.f,0.f);
        #pragma unroll 2
        for (int k4 = 0; k4 < 16; ++k4) {
            float4 h = h4[k4];
            float4 w0 = *(const float4*)&W2[(4 * k4 + 0) * 20 + c0];
            float4 w1 = *(const float4*)&W2[(4 * k4 + 1) * 20 + c0];
            float4 w2 = *(const float4*)&W2[(4 * k4 + 2) * 20 + c0];
            float4 w3 = *(const float4*)&W2[(4 * k4 + 3) * 20 + c0];
            acc.x += h.x * w0.x + h.y * w1.x + h.z * w2.x + h.w * w3.x;
            acc.y += h.x * w0.y + h.y * w1.y + h.z * w2.y + h.w * w3.y;
            acc.z += h.x * w0.z + h.y * w1.z + h.z * w2.z + h.w * w3.z;
            acc.w += h.x * w0.w + h.y * w1.w + h.z * w2.w + h.w * w3.w;
        }
        float d = disH[i];
        *(float4*)&T20x[i * 20 + c0] = make_float4(d*acc.x, d*acc.y, d*acc.z, d*acc.w);
    }
    __syncthreads();

    // ---- P6: H2 quad = lrelu(disH*(Ag_block @ T20x + self) + b2) — 555 items ----
    for (int o = tid; o < 555; o += NT) {
        int i = o / 5, c0 = (o % 5) * 4;
        if (i == 55) { *(float4*)&H2[i * 20 + c0] = make_float4(0.f,0.f,0.f,0.f); continue; }
        int jb = (i < 56) ? 0 : 56;
        float4 acc = make_float4(0.f,0.f,0.f,0.f);
        #pragma unroll 2
        for (int j4 = 0; j4 < 14; ++j4) {
            float4 a  = *(const float4*)&Ag[i * NR + jb + 4 * j4];
            float4 t0 = *(const float4*)&T20x[(jb + 4 * j4 + 0) * 20 + c0];
            float4 t1 = *(const float4*)&T20x[(jb + 4 * j4 + 1) * 20 + c0];
            float4 t2 = *(const float4*)&T20x[(jb + 4 * j4 + 2) * 20 + c0];
            float4 t3 = *(const float4*)&T20x[(jb + 4 * j4 + 3) * 20 + c0];
            acc.x += a.x * t0.x + a.y * t1.x + a.z * t2.x + a.w * t3.x;
            acc.y += a.x * t0.y + a.y * t1.y + a.z * t2.y + a.w * t3.y;
            acc.z += a.x * t0.z + a.y * t1.z + a.z * t2.z + a.w * t3.z;
            acc.w += a.x * t0.w + a.y * t1.w + a.z * t2.w + a.w * t3.w;
        }
        float4 self = *(const float4*)&T20x[i * 20 + c0];
        float4 bv = *(const float4*)&((i < 56) ? bl2 : br2)[c0];
        float dh = disH[i];
        float4 r;
        r.x = lrelu(dh * (acc.x + self.x) + bv.x);
        r.y = lrelu(dh * (acc.y + self.y) + bv.y);
        r.z = lrelu(dh * (acc.z + self.z) + bv.z);
        r.w = lrelu(dh * (acc.w + self.w) + bv.w);
        *(float4*)&H2[i * 20 + c0] = r;
    }
    __syncthreads();

    // ---- P7: T20x quad = disG .* (H2 @ Wg1s) — 560 items ----
    for (int o = tid; o < 560; o += NT) {
        int i = o / 5, c0 = (o % 5) * 4;
        if (i == 111) { *(float4*)&T20x[i * 20 + c0] = make_float4(0.f,0.f,0.f,0.f); continue; }
        float4 acc = make_float4(0.f,0.f,0.f,0.f);
        #pragma unroll 4
        for (int k = 0; k < 20; ++k) {
            float h = H2[i * 20 + k];
            float4 w = *(const float4*)&Wg1s[k * 20 + c0];
            acc.x += h * w.x; acc.y += h * w.y; acc.z += h * w.z; acc.w += h * w.w;
        }
        float d = disG[i];
        *(float4*)&T20x[i * 20 + c0] = make_float4(d*acc.x, d*acc.y, d*acc.z, d*acc.w);
    }
    __syncthreads();

    // ---- P8: H2g quad = lrelu(disG*(Ag @ T20x + self) + bg1) — 555 items ----
    for (int o = tid; o < 555; o += NT) {
        int i = o / 5, c0 = (o % 5) * 4;
        float4 acc = make_float4(0.f,0.f,0.f,0.f);
        #pragma unroll 2
        for (int j4 = 0; j4 < 28; ++j4) {
            float4 a  = *(const float4*)&Ag[i * NR + 4 * j4];
            float4 t0 = *(const float4*)&T20x[(4 * j4 + 0) * 20 + c0];
            float4 t1 = *(const float4*)&T20x[(4 * j4 + 1) * 20 + c0];
            float4 t2 = *(const float4*)&T20x[(4 * j4 + 2) * 20 + c0];
            float4 t3 = *(const float4*)&T20x[(4 * j4 + 3) * 20 + c0];
            acc.x += a.x * t0.x + a.y * t1.x + a.z * t2.x + a.w * t3.x;
            acc.y += a.x * t0.y + a.y * t1.y + a.z * t2.y + a.w * t3.y;
            acc.z += a.x * t0.z + a.y * t1.z + a.z * t2.z + a.w * t3.z;
            acc.w += a.x * t0.w + a.y * t1.w + a.z * t2.w + a.w * t3.w;
        }
        float4 self = *(const float4*)&T20x[i * 20 + c0];
        float4 bv = *(const float4*)&bg1[c0];
        float dg = disG[i];
        float4 r;
        r.x = lrelu(dg * (acc.x + self.x) + bv.x);
        r.y = lrelu(dg * (acc.y + self.y) + bv.y);
        r.z = lrelu(dg * (acc.z + self.z) + bv.z);
        r.w = lrelu(dg * (acc.w + self.w) + bv.w);
        *(float4*)&H2g[i * 20 + c0] = r;
    }
    __syncthreads();

    // ---- P9a: u = H2g.Wrel ; v = H2g.Wroot ----
    if (tid < 112) {
        if (tid == 111) { disC[111] = 0.f; scoreS[111] = 0.f; }
        else {
            float uu = 0.f, vv = 0.f;
            #pragma unroll 4
            for (int c = 0; c < 20; ++c) {
                float h = H2g[tid * 20 + c];
                uu += h * Wrel[c];
                vv += h * Wroot[c];
            }
            disC[tid] = uu; scoreS[tid] = vv;
        }
    }
    __syncthreads();

    // ---- P9b: score[i] = tanh(Ag row i . u + v[i] + brel) ----
    {
        float brel0 = brel[0];
        #pragma unroll 1
        for (int k = 0; k < 7; ++k) {
            int r = wv + 16 * k;
            if (r >= N) continue;
            float p = Ag[r * NR + lane] * disC[lane];
            if (lane < 48) p += Ag[r * NR + 64 + lane] * disC[64 + lane];
            #pragma unroll
            for (int m = 1; m < 64; m <<= 1) p += __shfl_xor(p, m);
            if (lane == 0) scoreS[r] = tanhf(p + scoreS[r] + brel0);
        }
    }
    __syncthreads();

    // ---- P10: rank, perm, sp ; zero Ap ----
    if (tid < N) {
        float si = scoreS[tid];
        int oi = d_P2O[tid];
        int r = 0;
        #pragma unroll 4
        for (int j = 0; j < N; ++j) {
            float sj = scoreS[j];
            r += (sj > si || (sj == si && d_P2O[j] < oi)) ? 1 : 0;
        }
        mapRank[tid] = (r < KP) ? r : -1;
        if (r < KP) permSh[r] = tid;
    }
    if (tid == N) mapRank[111] = -1;
    for (int o = tid; o < KP * APs; o += NT) Ap[o] = 0.f;
    __syncthreads();
    if (tid < N && mapRank[tid] >= 0) {
        int oi = d_P2O[tid], pos = 0;
        #pragma unroll 4
        for (int j = 0; j < N; ++j) pos += (mapRank[j] >= 0 && d_P2O[j] < oi) ? 1 : 0;
        spSh[pos] = tid;
    }
    __syncthreads();
    // ---- P11: scatter filtered adjacency (rank space) ----
    #pragma unroll 2
    for (int e = tid; e < NE; e += NT) {
        int sr = o2rS[edge_index[e]];
        int tr = o2rS[edge_index[NE + e]];
        int ms = mapRank[sr], mt = mapRank[tr];
        if (ms >= 0 && mt >= 0 && ms != mt) atomicAdd(&Ap[mt * APs + ms], 1.f);
    }
    __syncthreads();

    // ---- P12: disC from column sums of Ap ----
    if (tid < APs) {
        if (tid >= KP) disC[tid] = 0.f;
        else {
            float d0 = 0.f, d1 = 0.f;
            #pragma unroll 4
            for (int a = 0; a < KP; a += 2) {
                d0 += Ap[a * APs + tid];
                d1 += Ap[(a + 1) * APs + tid];
            }
            float d = d0 + d1;
            disC[tid] = (d > 0.f) ? 1.f / sqrtf(d) : 0.f;
        }
    }
    __syncthreads();

    // ---- P13: TC quad = disC .* h2[node]; stage Wcs; zero TC2 tail ----
    for (int o = tid; o < 520; o += NT) {
        int bq = o / 5, c0 = (o % 5) * 4;
        float4 h = *(const float4*)&H2g[o2rS[bq] * 20 + c0];
        float d = disC[bq];
        *(float4*)&TC[bq * 20 + c0] = make_float4(d*h.x, d*h.y, d*h.z, d*h.w);
    }
    #pragma unroll 2
    for (int o = tid; o < 1120; o += NT) {
        Wcs[o] = Wc0[o]; Wcs[1120 + o] = Wc1[o]; Wcs[2240 + o] = Wc2[o];
    }
    if (tid < 80) TC2[2000 + tid] = 0.f;   // rows 100..103 for P15b float4 reads
    __syncthreads();

    // ---- P14: Tx1 quad = -disC*(Ap@TC); TC2 = disC*Tx1 — 500 items ----
    for (int o = tid; o < 500; o += NT) {
        int a = o / 5, c0 = (o % 5) * 4;
        float4 acc = make_float4(0.f,0.f,0.f,0.f);
        #pragma unroll 2
        for (int j4 = 0; j4 < 26; ++j4) {
            float4 av = *(const float4*)&Ap[a * APs + 4 * j4];
            float4 t0 = *(const float4*)&TC[(4 * j4 + 0) * 20 + c0];
            float4 t1 = *(const float4*)&TC[(4 * j4 + 1) * 20 + c0];
            float4 t2 = *(const float4*)&TC[(4 * j4 + 2) * 20 + c0];
            float4 t3 = *(const float4*)&TC[(4 * j4 + 3) * 20 + c0];
            acc.x += av.x * t0.x + av.y * t1.x + av.z * t2.x + av.w * t3.x;
            acc.y += av.x * t0.y + av.y * t1.y + av.z * t2.y + av.w * t3.y;
            acc.z += av.x * t0.z + av.y * t1.z + av.z * t2.z + av.w * t3.z;
            acc.w += av.x * t0.w + av.y * t1.w + av.z * t2.w + av.w * t3.w;
        }
        float d = disC[a];
        float4 t = make_float4(-d*acc.x, -d*acc.y, -d*acc.z, -d*acc.w);
        *(float4*)&Tx1[a * 20 + c0] = t;
        *(float4*)&TC2[a * 20 + c0] = make_float4(d*t.x, d*t.y, d*t.z, d*t.w);
    }
    __syncthreads();

    // ---- P15b: Tx2 quad = -2*disC*(Ap@TC2) - h2[node] — 500 items ----
    for (int o = tid; o < 500; o += NT) {
        int a = o / 5, c0 = (o % 5) * 4;
        float4 acc = make_float4(0.f,0.f,0.f,0.f);
        #pragma unroll 2
        for (int j4 = 0; j4 < 26; ++j4) {
            float4 av = *(const float4*)&Ap[a * APs + 4 * j4];
            float4 t0 = *(const float4*)&TC2[(4 * j4 + 0) * 20 + c0];
            float4 t1 = *(const float4*)&TC2[(4 * j4 + 1) * 20 + c0];
            float4 t2 = *(const float4*)&TC2[(4 * j4 + 2) * 20 + c0];
            float4 t3 = *(const float4*)&TC2[(4 * j4 + 3) * 20 + c0];
            acc.x += av.x * t0.x + av.y * t1.x + av.z * t2.x + av.w * t3.x;
            acc.y += av.x * t0.y + av.y * t1.y + av.z * t2.y + av.w * t3.y;
            acc.z += av.x * t0.z + av.y * t1.z + av.z * t2.z + av.w * t3.z;
            acc.w += av.x * t0.w + av.y * t1.w + av.z * t2.w + av.w * t3.w;
        }
        float d2 = -2.f * disC[a];
        float4 h = *(const float4*)&H2g[o2rS[a] * 20 + c0];
        *(float4*)&Tx2[a * 20 + c0] =
            make_float4(d2*acc.x - h.x, d2*acc.y - h.y, d2*acc.z - h.z, d2*acc.w - h.w);
    }
    __syncthreads();

    // ---- P16 (+fused softmax): logits with k4-quad reads; immediate stores
    //      (s2S no longer aliases Tx1/Tx2 -> no deferred arrays, no mid barrier). ----
    {
        float bcv = (lane < CA) ? bc[lane] : 0.f;
        const int base = wv * 7;
        float acc[7] = {0,0,0,0,0,0,0};
        int ho[7], txo[7], in7[7];
        #pragma unroll
        for (int u = 0; u < 7; ++u) {
            int i = base + u;
            int ic = (i < N) ? i : (N - 1);
            ho[u]  = o2rS[ic] * 20;
            in7[u] = (ic < KP) ? 1 : 0;
            txo[u] = ((ic < KP) ? ic : 0) * 20;
        }
        #pragma unroll 1
        for (int k4 = 0; k4 < 5; ++k4) {
            float w0[4], w1[4], w2[4];
            #pragma unroll
            for (int q = 0; q < 4; ++q) {
                int k = 4 * k4 + q;
                w0[q] = Wcs[k * CA + lane];
                w1[q] = Wcs[1120 + k * CA + lane];
                w2[q] = Wcs[2240 + k * CA + lane];
            }
            #pragma unroll
            for (int u = 0; u < 7; ++u) {
                float4 h = *(const float4*)&H2g[ho[u] + 4 * k4];      // broadcast
                float4 t1, t2;
                if (in7[u]) {
                    t1 = *(const float4*)&Tx1[txo[u] + 4 * k4];
                    t2 = *(const float4*)&Tx2[txo[u] + 4 * k4];
                } else {
                    t1 = make_float4(0.f,0.f,0.f,0.f);
                    t2 = make_float4(-h.x,-h.y,-h.z,-h.w);
                }
                acc[u] += h.x*w0[0] + h.y*w0[1] + h.z*w0[2] + h.w*w0[3]
                        + t1.x*w1[0] + t1.y*w1[1] + t1.z*w1[2] + t1.w*w1[3]
                        + t2.x*w2[0] + t2.y*w2[1] + t2.z*w2[2] + t2.w*w2[3];
            }
        }
        // per-row double softmax; store immediately (distinct LDS regions)
        #pragma unroll 1
        for (int u = 0; u < 7; ++u) {
            int i = base + u;
            float v = (lane < CA) ? acc[u] + bcv : -3.4e38f;
            float m = v;
            #pragma unroll
            for (int s = 1; s < 64; s <<= 1) m = fmaxf(m, __shfl_xor(m, s));
            float e = (lane < CA) ? expf(v - m) : 0.f;
            float sum = e;
            #pragma unroll
            for (int s = 1; s < 64; s <<= 1) sum += __shfl_xor(sum, s);
            float p1 = e / sum;
            float m2 = (lane < CA) ? p1 : -3.4e38f;
            #pragma unroll
            for (int s = 1; s < 64; s <<= 1) m2 = fmaxf(m2, __shfl_xor(m2, s));
            float e2 = (lane < CA) ? expf(p1 - m2) : 0.f;
            float sum2 = e2;
            #pragma unroll
            for (int s = 1; s < 64; s <<= 1) sum2 += __shfl_xor(sum2, s);
            if (i < N && lane < CA) {
                assS[i * CA + lane] = p1;
                s2S[i * CA + lane]  = e2 / sum2;
            }
        }
    }
    __syncthreads();

    // ---- P17: Hc quad = s2^T @ h2 — 280 items ----
    for (int o = tid; o < 280; o += NT) {
        int q = o / 5, c0 = (o % 5) * 4;
        float4 acc = make_float4(0.f,0.f,0.f,0.f);
        #pragma unroll 2
        for (int r = 0; r < N; ++r) {
            float s = s2S[d_P2O[r] * CA + q];
            float4 h = *(const float4*)&H2g[r * 20 + c0];
            acc.x += s * h.x; acc.y += s * h.y; acc.z += s * h.z; acc.w += s * h.w;
        }
        *(float4*)&HcS[q * 20 + c0] = acc;
    }
    __syncthreads();

    // ---- P18: out quad = pooled + inter @ Hc — q4-quad assS reads ----
    for (int o = tid; o < 500; o += NT) {
        int k = o / 5, c0 = (o % 5) * 4;
        int rp = permSh[k];
        float sc = scoreS[rp];
        float4 hq = *(const float4*)&H2g[rp * 20 + c0];
        float4 v = make_float4(sc*hq.x, sc*hq.y, sc*hq.z, sc*hq.w);
        int oi = d_P2O[spSh[k]];
        if (oi < 110) {
            float4 acc = make_float4(0.f,0.f,0.f,0.f);
            #pragma unroll 2
            for (int q4 = 0; q4 < 14; ++q4) {
                float4 s  = *(const float4*)&assS[oi * CA + 4 * q4];  // broadcast
                float4 h0 = *(const float4*)&HcS[(4 * q4 + 0) * 20 + c0];
                float4 h1 = *(const float4*)&HcS[(4 * q4 + 1) * 20 + c0];
                float4 h2 = *(const float4*)&HcS[(4 * q4 + 2) * 20 + c0];
                float4 h3 = *(const float4*)&HcS[(4 * q4 + 3) * 20 + c0];
                acc.x += s.x * h0.x + s.y * h1.x + s.z * h2.x + s.w * h3.x;
                acc.y += s.x * h0.y + s.y * h1.y + s.z * h2.y + s.w * h3.y;
                acc.z += s.x * h0.z + s.y * h1.z + s.z * h2.z + s.w * h3.z;
                acc.w += s.x * h0.w + s.y * h1.w + s.z * h2.w + s.w * h3.w;
            }
            v.x += acc.x; v.y += acc.y; v.z += acc.z; v.w += acc.w;
        }
        *(float4*)&out[(size_t)b * (KP * 20) + k * 20 + c0] = v;
    }
}

extern "C" void kernel_launch(void* const* d_in, const int* in_sizes, int n_in,
                              void* d_out, int out_size, void* d_ws, size_t ws_size,
                              hipStream_t stream) {
    const float* features   = (const float*)d_in[0];
    const float* edge_attr  = (const float*)d_in[1];
    // d_in[2] = adj (unused by reference)
    const int*   edge_index = (const int*)d_in[3];
    const float* Wl1 = (const float*)d_in[4];
    const float* bl1 = (const float*)d_in[5];
    const float* Wr1 = (const float*)d_in[6];
    const float* br1 = (const float*)d_in[7];
    const float* Wl2 = (const float*)d_in[8];
    const float* bl2 = (const float*)d_in[9];
    const float* Wr2 = (const float*)d_in[10];
    const float* br2 = (const float*)d_in[11];
    const float* Wg1 = (const float*)d_in[12];
    const float* bg1 = (const float*)d_in[13];
    const float* Wrel = (const float*)d_in[14];
    const float* brel = (const float*)d_in[15];
    const float* Wroot = (const float*)d_in[16];
    const float* Wc0 = (const float*)d_in[17];
    const float* Wc1 = (const float*)d_in[18];
    const float* Wc2 = (const float*)d_in[19];
    const float* bc  = (const float*)d_in[20];
    float* out = (float*)d_out;

    int B = in_sizes[0] / (N * N);
    brain_fused<<<dim3(B), dim3(NT), 0, stream>>>(
        features, edge_attr, edge_index,
        Wl1, bl1, Wr1, br1, Wl2, bl2, Wr2, br2, Wg1, bg1,
        Wrel, brel, Wroot, Wc0, Wc1, Wc2, bc, out);
}